// Round 11
// baseline (340.016 us; speedup 1.0000x reference)
//
#include <hip/hip_runtime.h>
#include <hip/hip_bf16.h>

// RelativeGlobalAttention: B=2, S=2048, D=512, H=8, DH=64, MAX_SEQ=2048
// out0 = attention output (B,S,D); out1 = attn probs (B,H,S,S); concatenated.
//
// Identity: srel[l,k] = q[l].E[2047-l+k] for k<=l, else 0.
// logits = (QK^T + srel)/8; causal mask => masked probs exactly 0.
// No-max softmax: exp(v)/sum(exp(v)) == reference softmax up to fp32 rounding.
//
// R11 theory: the wall is per-CU L2-read concurrency (every K/E/V load is an
// L1 miss on a wave-private tile; misses never merge; ~2-3 TB/s effective on
// both attn AND gemms). Fix: 4 waves/block = 4 strips of one 64-row Q-block,
// iterating the SAME K-tile in barrier lockstep -> K/V loads merge 4x, E 75%.
// K-parity (kh) split doubles parallelism; lsum -> separate paired kernel;
// PV partials Op0/Op1 summed exactly inside gemm_o (2nd MFMA, distributive).

namespace {
constexpr int kS  = 2048;
constexpr int kD  = 512;
constexpr int kH  = 8;
constexpr int kDH = 64;
constexpr int kB  = 2;

typedef __attribute__((ext_vector_type(8))) short short8;   // 8 x bf16
typedef __attribute__((ext_vector_type(4))) float f32x4;
}

#define WAVE_LDS_FENCE() do { \
    asm volatile("s_waitcnt lgkmcnt(0)" ::: "memory"); \
    __builtin_amdgcn_sched_barrier(0); \
} while (0)

__device__ __forceinline__ f32x4 mfma16(short8 a, short8 b, f32x4 c) {
    return __builtin_amdgcn_mfma_f32_16x16x32_bf16(a, b, c, 0, 0, 0);
}

__device__ __forceinline__ short bfbits(float f) {
    __hip_bfloat16 h = __float2bfloat16(f);
    return *reinterpret_cast<short*>(&h);
}

// ---------------------------------------------------------------------------
// conv: W (512x512 fp32 row-major) -> Wt (bf16 col-major [c][k]) x4; E -> bf16
// ---------------------------------------------------------------------------
__global__ __launch_bounds__(256)
void convw_kernel(const float* __restrict__ Wq, const float* __restrict__ Wk,
                  const float* __restrict__ Wv, const float* __restrict__ Wo,
                  const float* __restrict__ E,
                  ushort* __restrict__ Wqt, ushort* __restrict__ Wkt,
                  ushort* __restrict__ Wvt, ushort* __restrict__ Wot,
                  ushort* __restrict__ eb)
{
    const int z = blockIdx.z;
    const int tid = threadIdx.x;
    if (z == 4) {   // E: 2048x64 = 131072 elems
        const int idx = ((blockIdx.y * 8 + blockIdx.x) * 256 + tid) * 8;
        const float4 x = *reinterpret_cast<const float4*>(E + idx);
        const float4 y = *reinterpret_cast<const float4*>(E + idx + 4);
        short8 r;
        r[0] = bfbits(x.x); r[1] = bfbits(x.y); r[2] = bfbits(x.z); r[3] = bfbits(x.w);
        r[4] = bfbits(y.x); r[5] = bfbits(y.y); r[6] = bfbits(y.z); r[7] = bfbits(y.w);
        *reinterpret_cast<short8*>(eb + idx) = r;
        return;
    }
    const float* W = (z == 0) ? Wq : (z == 1) ? Wk : (z == 2) ? Wv : Wo;
    ushort* Wt = (z == 0) ? Wqt : (z == 1) ? Wkt : (z == 2) ? Wvt : Wot;

    __shared__ float Ws[64][65];
    const int k0 = blockIdx.x * 64;
    const int c0 = blockIdx.y * 64;
    const int cc = tid & 63;
    const int rq = tid >> 6;
    #pragma unroll
    for (int ii = 0; ii < 16; ++ii) {
        const int r = ii * 4 + rq;
        Ws[r][cc] = W[(size_t)(k0 + r) * kD + c0 + cc];
    }
    __syncthreads();
    #pragma unroll
    for (int ii = 0; ii < 16; ++ii) {
        const int r = ii * 4 + rq;
        Wt[(size_t)(c0 + r) * kD + k0 + cc] = (ushort)bfbits(Ws[cc][r]);
    }
}

// q_in/k_in/v_in fp32 (B,S,D) -> bf16
__global__ __launch_bounds__(256)
void cvta_kernel(const float* __restrict__ q, const float* __restrict__ k,
                 const float* __restrict__ v,
                 ushort* __restrict__ qb, ushort* __restrict__ kb,
                 ushort* __restrict__ vb)
{
    const int z = blockIdx.z;
    const float* src = (z == 0) ? q : (z == 1) ? k : v;
    ushort* dst = (z == 0) ? qb : (z == 1) ? kb : vb;
    const int idx = (blockIdx.x * 256 + threadIdx.x) * 8;
    const float4 x = *reinterpret_cast<const float4*>(src + idx);
    const float4 y = *reinterpret_cast<const float4*>(src + idx + 4);
    short8 r;
    r[0] = bfbits(x.x); r[1] = bfbits(x.y); r[2] = bfbits(x.z); r[3] = bfbits(x.w);
    r[4] = bfbits(y.x); r[5] = bfbits(y.y); r[6] = bfbits(y.z); r[7] = bfbits(y.w);
    *reinterpret_cast<short8*>(dst + idx) = r;
}

// ---------------------------------------------------------------------------
// MFMA GEMM. TWO_A: C = (A0 + A1) @ W via two MFMAs (exact, distributive).
// MODE: 0 = fp32 (B,S,D); 1 = bf16 (B,H,S,DH); 2 = bf16 (B,H,DH,S)
// ---------------------------------------------------------------------------
template<int MODE, bool TWO_A>
__device__ __forceinline__
void gemm_core(const ushort* __restrict__ A, const ushort* __restrict__ A2,
               const ushort* __restrict__ Wt,
               const float* __restrict__ bias, void* __restrict__ out)
{
    const int tid  = threadIdx.x;
    const int w    = tid >> 6;
    const int lane = tid & 63;
    const int g    = lane >> 4;
    const int n15  = lane & 15;
    const int r0   = blockIdx.x * 64 + w * 16;
    const int c0   = blockIdx.y * 32;

    f32x4 acc0 = {0.f, 0.f, 0.f, 0.f};
    f32x4 acc1 = {0.f, 0.f, 0.f, 0.f};
    const size_t aoff = (size_t)(r0 + n15) * kD + g * 8;
    const ushort* b0p  = Wt + (size_t)(c0 + n15) * kD + g * 8;
    const ushort* b1p  = Wt + (size_t)(c0 + 16 + n15) * kD + g * 8;

    #pragma unroll 4
    for (int k0 = 0; k0 < kD; k0 += 32) {
        const short8 a  = *reinterpret_cast<const short8*>(A + aoff + k0);
        const short8 b0 = *reinterpret_cast<const short8*>(b0p + k0);
        const short8 b1 = *reinterpret_cast<const short8*>(b1p + k0);
        acc0 = mfma16(a, b0, acc0);
        acc1 = mfma16(a, b1, acc1);
        if (TWO_A) {
            const short8 a2 = *reinterpret_cast<const short8*>(A2 + aoff + k0);
            acc0 = mfma16(a2, b0, acc0);
            acc1 = mfma16(a2, b1, acc1);
        }
    }

    #pragma unroll
    for (int cg = 0; cg < 2; ++cg) {
        const f32x4 acc = cg ? acc1 : acc0;
        const int c = c0 + cg * 16 + n15;
        const float bb = bias[c];
        const int h = c >> 6, d = c & (kDH - 1);
        #pragma unroll
        for (int j = 0; j < 4; ++j) {
            const int r = r0 + g * 4 + j;
            const float val = acc[j] + bb;
            const int b = r >> 11, s2 = r & (kS - 1);
            if (MODE == 0) {
                ((float*)out)[(size_t)r * kD + c] = val;
            } else if (MODE == 1) {
                ((ushort*)out)[((size_t)(b * kH + h) * kS + s2) * kDH + d] = (ushort)bfbits(val);
            } else {
                ((ushort*)out)[((size_t)(b * kH + h) * kDH + d) * kS + s2] = (ushort)bfbits(val);
            }
        }
    }
}

__global__ __launch_bounds__(256)
void gemm_qkv_kernel(const ushort* __restrict__ qb, const ushort* __restrict__ kb,
                     const ushort* __restrict__ vb,
                     const ushort* __restrict__ Wqt, const ushort* __restrict__ Wkt,
                     const ushort* __restrict__ Wvt,
                     const float* __restrict__ bq, const float* __restrict__ bk,
                     const float* __restrict__ bv,
                     ushort* __restrict__ qh, ushort* __restrict__ kh,
                     ushort* __restrict__ vt)
{
    const int z = blockIdx.z;
    const ushort* A    = (z == 0) ? qb  : (z == 1) ? kb  : vb;
    const ushort* Wt   = (z == 0) ? Wqt : (z == 1) ? Wkt : Wvt;
    const float*  bias = (z == 0) ? bq  : (z == 1) ? bk  : bv;
    void*         out  = (z == 0) ? (void*)qh : (z == 1) ? (void*)kh : (void*)vt;
    if (z == 2) gemm_core<2, false>(A, nullptr, Wt, bias, out);
    else        gemm_core<1, false>(A, nullptr, Wt, bias, out);
}

__global__ __launch_bounds__(256)
void gemm_o_kernel(const ushort* __restrict__ Op0, const ushort* __restrict__ Op1,
                   const ushort* __restrict__ Wot,
                   const float* __restrict__ bo, float* __restrict__ out)
{
    gemm_core<0, true>(Op0, Op1, Wot, bo, out);
}

// ---------------------------------------------------------------------------
// attn_lsum: row sums (pass A). Block = (bh, qpair p, kh): phase q = p then
// 31-p. 4 waves = strips 4q+j (all T = q+1); waves iterate the SAME tile
// t = kh, kh+2, ... in barrier lockstep -> K loads merge across waves, E 75%.
// grid (16,16,2) x 256. Writes lsum partial lp[kh].
// ---------------------------------------------------------------------------
__global__ __launch_bounds__(256, 4)
void attn_lsum_kernel(const ushort* __restrict__ qh, const ushort* __restrict__ khp,
                      const ushort* __restrict__ eb, float* __restrict__ lp)
{
    const int bh   = blockIdx.x;
    const int p    = blockIdx.y;
    const int kh   = blockIdx.z;
    const int tid  = threadIdx.x;
    const int w    = tid >> 6;
    const int lane = tid & 63;
    const int g    = lane >> 4;
    const int n15  = lane & 15;
    const size_t bhS = (size_t)bh * kS;

    int  srcl[4];
    bool condj[4];
    #pragma unroll
    for (int j = 0; j < 4; ++j) {
        const int d = n15 + 15 - (g * 4 + j);
        srcl[j]  = (lane & 48) | (d & 15);
        condj[j] = (d >= 16);
    }

    float* lph = lp + (size_t)kh * 16 * kS;

    #pragma unroll
    for (int ph = 0; ph < 2; ++ph) {
        const int q  = ph ? (31 - p) : p;
        const int l0 = q * 64 + w * 16;          // wave w = strip 4q+w
        const int T  = q + 1;

        const ushort* qrow = qh + (bhS + l0 + n15) * kDH;
        const short8 aq0 = *reinterpret_cast<const short8*>(qrow + g * 8);
        const short8 aq1 = *reinterpret_cast<const short8*>(qrow + 32 + g * 8);

        float lsum[4] = {0.f, 0.f, 0.f, 0.f};
        for (int t = kh; t < T; t += 2) {
            __syncthreads();                     // keep waves in phase (L1 merge)
            const int k0 = t * 64;
            float sl[4][4];
            #pragma unroll
            for (int nt = 0; nt < 4; ++nt) {
                const ushort* krow = khp + (bhS + k0 + nt * 16 + n15) * kDH;
                f32x4 acc = {0.f, 0.f, 0.f, 0.f};
                acc = mfma16(aq0, *reinterpret_cast<const short8*>(krow + g * 8), acc);
                acc = mfma16(aq1, *reinterpret_cast<const short8*>(krow + 32 + g * 8), acc);
                #pragma unroll
                for (int j = 0; j < 4; ++j) sl[nt][j] = acc[j];
            }
            const int m_lo = 2032 + k0 - l0;
            f32x4 qe[5];
            #pragma unroll
            for (int nt = 0; nt < 5; ++nt) {
                int er = m_lo + nt * 16 + n15;
                if (er > kS - 1) er = kS - 1;    // clamped rows only feed masked elems
                const ushort* erow = eb + (size_t)er * kDH;
                f32x4 acc = {0.f, 0.f, 0.f, 0.f};
                acc = mfma16(aq0, *reinterpret_cast<const short8*>(erow + g * 8), acc);
                qe[nt] = mfma16(aq1, *reinterpret_cast<const short8*>(erow + 32 + g * 8), acc);
            }
            #pragma unroll
            for (int j = 0; j < 4; ++j) {
                float sh[5];
                #pragma unroll
                for (int q5 = 0; q5 < 5; ++q5) sh[q5] = __shfl(qe[q5][j], srcl[j]);
                const int lr = g * 4 + j;
                #pragma unroll
                for (int nt = 0; nt < 4; ++nt) {
                    const float rel = condj[j] ? sh[nt + 1] : sh[nt];
                    const int ki = nt * 16 + n15;
                    float v = (sl[nt][j] + rel) * 0.125f;
                    v = fminf(v, 60.f);
                    lsum[j] += (k0 + ki <= l0 + lr) ? __expf(v) : 0.f;
                }
            }
        }
        #pragma unroll
        for (int j = 0; j < 4; ++j) {
            float s = lsum[j];
            #pragma unroll
            for (int off = 1; off < 16; off <<= 1) s += __shfl_xor(s, off);
            if (n15 == 0) lph[bhS + l0 + g * 4 + j] = s;
        }
        __syncthreads();                         // phase separation
    }
}

// ---------------------------------------------------------------------------
// attn_emit: pass B. Block = (bh, quad q, kh); 4 waves = strips 4q+j, same
// tile sequence t = kh, kh+2, .. 31 (16 slots/wave always -> uniform). Active
// slots: recompute scores, emit normalized probs (Pw staging, 256B nt
// stores), PV. Zero slots: 256B zero-fill. Wave-private O -> Op[kh] direct.
// grid (16,32,2) x 256.
// ---------------------------------------------------------------------------
__global__ __launch_bounds__(256, 4)
void attn_emit_kernel(const ushort* __restrict__ qh, const ushort* __restrict__ khp,
                      const ushort* __restrict__ vt, const ushort* __restrict__ eb,
                      const float* __restrict__ lp,
                      float* __restrict__ attn, ushort* __restrict__ Op)
{
    __shared__ __align__(16) char smem[17408];   // 4 waves x 16x68 f32

    const int bh   = blockIdx.x;
    const int q    = blockIdx.y;
    const int kh   = blockIdx.z;
    const int tid  = threadIdx.x;
    const int w    = tid >> 6;
    const int lane = tid & 63;
    const int g    = lane >> 4;
    const int n15  = lane & 15;
    const size_t bhS = (size_t)bh * kS;

    float* Pw = (float*)(smem + w * 4352);
    const int l0 = q * 64 + w * 16;
    const int T  = q + 1;

    const ushort* qrow = qh + (bhS + l0 + n15) * kDH;
    const short8 aq0 = *reinterpret_cast<const short8*>(qrow + g * 8);
    const short8 aq1 = *reinterpret_cast<const short8*>(qrow + 32 + g * 8);

    int  srcl[4];
    bool condj[4];
    #pragma unroll
    for (int j = 0; j < 4; ++j) {
        const int d = n15 + 15 - (g * 4 + j);
        srcl[j]  = (lane & 48) | (d & 15);
        condj[j] = (d >= 16);
    }

    const float* lp0 = lp;
    const float* lp1 = lp + (size_t)16 * kS;
    float linv[4];
    #pragma unroll
    for (int j = 0; j < 4; ++j) {
        const int row = l0 + g * 4 + j;
        linv[j] = 1.f / (lp0[bhS + row] + lp1[bhS + row]);
    }

    f32x4 o[4];
    #pragma unroll
    for (int nt = 0; nt < 4; ++nt) o[nt] = (f32x4){0.f, 0.f, 0.f, 0.f};

    const int rr4 = lane >> 4;
    const int cc4 = (lane & 15) * 4;

    for (int t = kh; t < 32; t += 2) {
        __syncthreads();                         // keep waves in phase (L1 merge)
        const int k0 = t * 64;
        if (t >= T) {                            // fully masked: 256B zero segments
            const f32x4 z = {0.f, 0.f, 0.f, 0.f};
            #pragma unroll
            for (int i = 0; i < 4; ++i) {
                const int row = i * 4 + rr4;
                __builtin_nontemporal_store(
                    z, reinterpret_cast<f32x4*>(attn + (bhS + l0 + row) * kS + k0 + cc4));
            }
            continue;
        }
        float sl[4][4];
        #pragma unroll
        for (int nt = 0; nt < 4; ++nt) {
            const ushort* krow = khp + (bhS + k0 + nt * 16 + n15) * kDH;
            f32x4 acc = {0.f, 0.f, 0.f, 0.f};
            acc = mfma16(aq0, *reinterpret_cast<const short8*>(krow + g * 8), acc);
            acc = mfma16(aq1, *reinterpret_cast<const short8*>(krow + 32 + g * 8), acc);
            #pragma unroll
            for (int j = 0; j < 4; ++j) sl[nt][j] = acc[j];
        }
        const int m_lo = 2032 + k0 - l0;
        f32x4 qe[5];
        #pragma unroll
        for (int nt = 0; nt < 5; ++nt) {
            int er = m_lo + nt * 16 + n15;
            if (er > kS - 1) er = kS - 1;
            const ushort* erow = eb + (size_t)er * kDH;
            f32x4 acc = {0.f, 0.f, 0.f, 0.f};
            acc = mfma16(aq0, *reinterpret_cast<const short8*>(erow + g * 8), acc);
            qe[nt] = mfma16(aq1, *reinterpret_cast<const short8*>(erow + 32 + g * 8), acc);
        }
        #pragma unroll
        for (int j = 0; j < 4; ++j) {
            float sh[5];
            #pragma unroll
            for (int q5 = 0; q5 < 5; ++q5) sh[q5] = __shfl(qe[q5][j], srcl[j]);
            const int lr = g * 4 + j;
            #pragma unroll
            for (int nt = 0; nt < 4; ++nt) {
                const float rel = condj[j] ? sh[nt + 1] : sh[nt];
                const int ki = nt * 16 + n15;
                float v = (sl[nt][j] + rel) * 0.125f;
                v = fminf(v, 60.f);
                const float pe = (k0 + ki <= l0 + lr) ? __expf(v) * linv[j] : 0.f;
                Pw[lr * 68 + ki] = pe;
            }
        }
        WAVE_LDS_FENCE();                        // Pw writes -> reads

        #pragma unroll
        for (int i = 0; i < 4; ++i) {            // 256B-contiguous attn stores
            const int row = i * 4 + rr4;
            const f32x4 pv4 = *reinterpret_cast<const f32x4*>(&Pw[row * 68 + cc4]);
            __builtin_nontemporal_store(
                pv4, reinterpret_cast<f32x4*>(attn + (bhS + l0 + row) * kS + k0 + cc4));
        }
        const f32x4 plo0 = *reinterpret_cast<const f32x4*>(&Pw[n15 * 68 + g * 8]);
        const f32x4 phi0 = *reinterpret_cast<const f32x4*>(&Pw[n15 * 68 + g * 8 + 4]);
        const f32x4 plo1 = *reinterpret_cast<const f32x4*>(&Pw[n15 * 68 + 32 + g * 8]);
        const f32x4 phi1 = *reinterpret_cast<const f32x4*>(&Pw[n15 * 68 + 32 + g * 8 + 4]);
        WAVE_LDS_FENCE();                        // Pw reads retired (WAR)

        short8 pa0, pa1;
        #pragma unroll
        for (int i = 0; i < 4; ++i) {
            pa0[i] = bfbits(plo0[i]); pa0[4 + i] = bfbits(phi0[i]);
            pa1[i] = bfbits(plo1[i]); pa1[4 + i] = bfbits(phi1[i]);
        }
        #pragma unroll
        for (int nt = 0; nt < 4; ++nt) {
            const ushort* vrow = vt + ((size_t)bh * kDH + nt * 16 + n15) * kS + k0;
            o[nt] = mfma16(pa0, *reinterpret_cast<const short8*>(vrow + g * 8), o[nt]);
            o[nt] = mfma16(pa1, *reinterpret_cast<const short8*>(vrow + 32 + g * 8), o[nt]);
        }
    }

    // wave-private O -> Op[kh] bf16 (B,S,D); no cross-wave combine needed
    ushort* oph = Op + (size_t)kh * kB * kS * kD;
    const int b = bh >> 3, h = bh & 7;
    #pragma unroll
    for (int nt = 0; nt < 4; ++nt)
        #pragma unroll
        for (int j = 0; j < 4; ++j)
            oph[((size_t)b * kS + l0 + g * 4 + j) * kD + h * kDH + nt * 16 + n15] =
                (ushort)bfbits(o[nt][j]);
}

// ---------------------------------------------------------------------------
extern "C" void kernel_launch(void* const* d_in, const int* in_sizes, int n_in,
                              void* d_out, int out_size, void* d_ws, size_t ws_size,
                              hipStream_t stream)
{
    const float* q_in = (const float*)d_in[0];
    const float* k_in = (const float*)d_in[1];
    const float* v_in = (const float*)d_in[2];
    const float* Wq = (const float*)d_in[4];
    const float* bq = (const float*)d_in[5];
    const float* Wk = (const float*)d_in[6];
    const float* bk = (const float*)d_in[7];
    const float* Wv = (const float*)d_in[8];
    const float* bv = (const float*)d_in[9];
    const float* Wo = (const float*)d_in[10];
    const float* bo = (const float*)d_in[11];
    const float* E  = (const float*)d_in[12];

    float* out  = (float*)d_out;                          // (B,S,D)
    float* attn = (float*)d_out + (size_t)kB * kS * kD;   // (B,H,S,S)

    // workspace (~40 MB)
    ushort* qh  = (ushort*)d_ws;          // (B,H,S,DH) bf16
    ushort* kh  = qh  + 2097152;          // (B,H,S,DH) bf16
    ushort* vt  = kh  + 2097152;          // (B,H,DH,S) bf16
    ushort* Op0 = vt  + 2097152;          // (B,S,D) bf16 PV partial kh=0
    ushort* Op1 = Op0 + 2097152;          // (B,S,D) bf16 PV partial kh=1
    ushort* qb  = Op1 + 2097152;          // (B,S,D) bf16 inputs
    ushort* kb  = qb  + 2097152;
    ushort* vb  = kb  + 2097152;
    ushort* eb  = vb  + 2097152;          // (2048,64) bf16
    ushort* Wqt = eb  + 131072;           // col-major 512x512 bf16
    ushort* Wkt = Wqt + 262144;
    ushort* Wvt = Wkt + 262144;
    ushort* Wot = Wvt + 262144;
    float*  lp  = (float*)(Wot + 262144); // 2 x (16,2048) lsum partials

    convw_kernel<<<dim3(8, 8, 5), 256, 0, stream>>>(Wq, Wk, Wv, Wo, E,
                                                    Wqt, Wkt, Wvt, Wot, eb);
    cvta_kernel<<<dim3(1024, 1, 3), 256, 0, stream>>>(q_in, k_in, v_in, qb, kb, vb);
    gemm_qkv_kernel<<<dim3(64, 16, 3), 256, 0, stream>>>(qb, kb, vb,
                                                         Wqt, Wkt, Wvt,
                                                         bq, bk, bv, qh, kh, vt);
    attn_lsum_kernel<<<dim3(16, 16, 2), 256, 0, stream>>>(qh, kh, eb, lp);
    attn_emit_kernel<<<dim3(16, 32, 2), 256, 0, stream>>>(qh, kh, vt, eb, lp, attn,
                                                          Op0);   // Op base; kh offsets inside
    gemm_o_kernel<<<dim3(64, 16), 256, 0, stream>>>(Op0, Op1, Wot, bo, out);
}

// Round 12
// 330.965 us; speedup vs baseline: 1.0273x; 1.0273x over previous
//
#include <hip/hip_runtime.h>
#include <hip/hip_bf16.h>

// RelativeGlobalAttention: B=2, S=2048, D=512, H=8, DH=64, MAX_SEQ=2048
// out0 = attention output (B,S,D); out1 = attn probs (B,H,S,S); concatenated.
//
// Identity: srel[l,k] = q[l].E[2047-l+k] for k<=l, else 0.
// logits = (QK^T + srel)/8; causal mask => masked probs exactly 0.
// No-max softmax: exp(v)/sum(exp(v)) == reference softmax up to fp32 rounding.
//
// R12 = R10 structure (best: 287us) + occupancy within register budget:
// attn __launch_bounds__(256,6): 24 waves/CU (cap 85 VGPR, kernel uses ~60).
// gemms __launch_bounds__(256,8): 32 waves/CU (cap 64 VGPR, kernel uses ~40).
// Theory: dependency-chain latency wall needs more TLP; R7 showed occupancy
// via register starvation fails, this buys it with headroom.

namespace {
constexpr int kS  = 2048;
constexpr int kD  = 512;
constexpr int kH  = 8;
constexpr int kDH = 64;
constexpr int kB  = 2;

typedef __attribute__((ext_vector_type(8))) short short8;   // 8 x bf16
typedef __attribute__((ext_vector_type(4))) float f32x4;
}

#define WAVE_LDS_FENCE() do { \
    asm volatile("s_waitcnt lgkmcnt(0)" ::: "memory"); \
    __builtin_amdgcn_sched_barrier(0); \
} while (0)

__device__ __forceinline__ f32x4 mfma16(short8 a, short8 b, f32x4 c) {
    return __builtin_amdgcn_mfma_f32_16x16x32_bf16(a, b, c, 0, 0, 0);
}

__device__ __forceinline__ short bfbits(float f) {
    __hip_bfloat16 h = __float2bfloat16(f);
    return *reinterpret_cast<short*>(&h);
}

// ---------------------------------------------------------------------------
// conv: W (512x512 fp32 row-major) -> Wt (bf16 col-major [c][k]) x4; E -> bf16
// ---------------------------------------------------------------------------
__global__ __launch_bounds__(256)
void convw_kernel(const float* __restrict__ Wq, const float* __restrict__ Wk,
                  const float* __restrict__ Wv, const float* __restrict__ Wo,
                  const float* __restrict__ E,
                  ushort* __restrict__ Wqt, ushort* __restrict__ Wkt,
                  ushort* __restrict__ Wvt, ushort* __restrict__ Wot,
                  ushort* __restrict__ eb)
{
    const int z = blockIdx.z;
    const int tid = threadIdx.x;
    if (z == 4) {   // E: 2048x64 = 131072 elems
        const int idx = ((blockIdx.y * 8 + blockIdx.x) * 256 + tid) * 8;
        const float4 x = *reinterpret_cast<const float4*>(E + idx);
        const float4 y = *reinterpret_cast<const float4*>(E + idx + 4);
        short8 r;
        r[0] = bfbits(x.x); r[1] = bfbits(x.y); r[2] = bfbits(x.z); r[3] = bfbits(x.w);
        r[4] = bfbits(y.x); r[5] = bfbits(y.y); r[6] = bfbits(y.z); r[7] = bfbits(y.w);
        *reinterpret_cast<short8*>(eb + idx) = r;
        return;
    }
    const float* W = (z == 0) ? Wq : (z == 1) ? Wk : (z == 2) ? Wv : Wo;
    ushort* Wt = (z == 0) ? Wqt : (z == 1) ? Wkt : (z == 2) ? Wvt : Wot;

    __shared__ float Ws[64][65];
    const int k0 = blockIdx.x * 64;
    const int c0 = blockIdx.y * 64;
    const int cc = tid & 63;
    const int rq = tid >> 6;
    #pragma unroll
    for (int ii = 0; ii < 16; ++ii) {
        const int r = ii * 4 + rq;
        Ws[r][cc] = W[(size_t)(k0 + r) * kD + c0 + cc];
    }
    __syncthreads();
    #pragma unroll
    for (int ii = 0; ii < 16; ++ii) {
        const int r = ii * 4 + rq;
        Wt[(size_t)(c0 + r) * kD + k0 + cc] = (ushort)bfbits(Ws[cc][r]);
    }
}

// q_in/k_in/v_in fp32 (B,S,D) -> bf16
__global__ __launch_bounds__(256)
void cvta_kernel(const float* __restrict__ q, const float* __restrict__ k,
                 const float* __restrict__ v,
                 ushort* __restrict__ qb, ushort* __restrict__ kb,
                 ushort* __restrict__ vb)
{
    const int z = blockIdx.z;
    const float* src = (z == 0) ? q : (z == 1) ? k : v;
    ushort* dst = (z == 0) ? qb : (z == 1) ? kb : vb;
    const int idx = (blockIdx.x * 256 + threadIdx.x) * 8;
    const float4 x = *reinterpret_cast<const float4*>(src + idx);
    const float4 y = *reinterpret_cast<const float4*>(src + idx + 4);
    short8 r;
    r[0] = bfbits(x.x); r[1] = bfbits(x.y); r[2] = bfbits(x.z); r[3] = bfbits(x.w);
    r[4] = bfbits(y.x); r[5] = bfbits(y.y); r[6] = bfbits(y.z); r[7] = bfbits(y.w);
    *reinterpret_cast<short8*>(dst + idx) = r;
}

// ---------------------------------------------------------------------------
// MFMA GEMM core (R10 form, higher occupancy bound)
// ---------------------------------------------------------------------------
template<int MODE>
__device__ __forceinline__
void gemm_core(const ushort* __restrict__ A, const ushort* __restrict__ Wt,
               const float* __restrict__ bias, void* __restrict__ out)
{
    const int tid  = threadIdx.x;
    const int w    = tid >> 6;
    const int lane = tid & 63;
    const int g    = lane >> 4;
    const int n15  = lane & 15;
    const int r0   = blockIdx.x * 64 + w * 16;
    const int c0   = blockIdx.y * 32;

    f32x4 acc0 = {0.f, 0.f, 0.f, 0.f};
    f32x4 acc1 = {0.f, 0.f, 0.f, 0.f};
    const ushort* arow = A  + (size_t)(r0 + n15) * kD + g * 8;
    const ushort* b0p  = Wt + (size_t)(c0 + n15) * kD + g * 8;
    const ushort* b1p  = Wt + (size_t)(c0 + 16 + n15) * kD + g * 8;

    #pragma unroll 4
    for (int k0 = 0; k0 < kD; k0 += 32) {
        const short8 a  = *reinterpret_cast<const short8*>(arow + k0);
        const short8 b0 = *reinterpret_cast<const short8*>(b0p + k0);
        const short8 b1 = *reinterpret_cast<const short8*>(b1p + k0);
        acc0 = mfma16(a, b0, acc0);
        acc1 = mfma16(a, b1, acc1);
    }

    #pragma unroll
    for (int cg = 0; cg < 2; ++cg) {
        const f32x4 acc = cg ? acc1 : acc0;
        const int c = c0 + cg * 16 + n15;
        const float bb = bias[c];
        const int h = c >> 6, d = c & (kDH - 1);
        #pragma unroll
        for (int j = 0; j < 4; ++j) {
            const int r = r0 + g * 4 + j;
            const float val = acc[j] + bb;
            const int b = r >> 11, s2 = r & (kS - 1);
            if (MODE == 0) {
                ((float*)out)[(size_t)r * kD + c] = val;
            } else if (MODE == 1) {
                ((ushort*)out)[((size_t)(b * kH + h) * kS + s2) * kDH + d] = (ushort)bfbits(val);
            } else {
                ((ushort*)out)[((size_t)(b * kH + h) * kDH + d) * kS + s2] = (ushort)bfbits(val);
            }
        }
    }
}

__global__ __launch_bounds__(256, 8)
void gemm_qkv_kernel(const ushort* __restrict__ qb, const ushort* __restrict__ kb,
                     const ushort* __restrict__ vb,
                     const ushort* __restrict__ Wqt, const ushort* __restrict__ Wkt,
                     const ushort* __restrict__ Wvt,
                     const float* __restrict__ bq, const float* __restrict__ bk,
                     const float* __restrict__ bv,
                     ushort* __restrict__ qh, ushort* __restrict__ kh,
                     ushort* __restrict__ vt)
{
    const int z = blockIdx.z;
    const ushort* A    = (z == 0) ? qb  : (z == 1) ? kb  : vb;
    const ushort* Wt   = (z == 0) ? Wqt : (z == 1) ? Wkt : Wvt;
    const float*  bias = (z == 0) ? bq  : (z == 1) ? bk  : bv;
    void*         out  = (z == 0) ? (void*)qh : (z == 1) ? (void*)kh : (void*)vt;
    if (z == 2) gemm_core<2>(A, Wt, bias, out);
    else        gemm_core<1>(A, Wt, bias, out);
}

__global__ __launch_bounds__(256, 8)
void gemm_o_kernel(const ushort* __restrict__ ohb, const ushort* __restrict__ Wot,
                   const float* __restrict__ bo, float* __restrict__ out)
{
    gemm_core<0>(ohb, Wot, bo, out);
}

// ---------------------------------------------------------------------------
// Fused attention (R10 structure). Block = (bh, strip) x 4 waves; wave w owns
// tiles t = w, w+4, ... Rel scores via in-register shfl diagonal gather.
// pe staged in wave-private fp32 LDS [16][68] -> 256B nt attn stores + PV
// A-frags. launch_bounds(256,6): 6 blocks/CU = 24 waves/CU, VGPR cap 85.
// grid (16,128) x 256.
// ---------------------------------------------------------------------------
__global__ __launch_bounds__(256, 6)
void attn_fused_kernel(const ushort* __restrict__ qh, const ushort* __restrict__ kh,
                       const ushort* __restrict__ vt, const ushort* __restrict__ eb,
                       float* __restrict__ attn, ushort* __restrict__ ohb)
{
    // LDS: [0,17408) Pf32 (4 waves x 16x68 f32) -- aliased by O_s after pass B
    //      [17408,17664) lsum_s ; O_s = [0,16384)
    __shared__ __align__(16) char smem[17664];

    const int bh    = blockIdx.x;
    const int strip = 127 - (int)blockIdx.y;     // big-work-first
    const int l0    = strip * 16;
    const int tid   = threadIdx.x;
    const int w     = tid >> 6;
    const int lane  = tid & 63;
    const int g     = lane >> 4;
    const int n15   = lane & 15;
    const size_t bhS = (size_t)bh * kS;

    float* Pw = (float*)(smem + w * 4352);       // 16 x 68 f32, wave-private
    float* lsum_s = (float*)(smem + 17408);

    const int T = ((l0 + 15) >> 6) + 1;          // causal 64-wide tiles

    const ushort* qrow = qh + (bhS + l0 + n15) * kDH;
    const short8 aq0 = *reinterpret_cast<const short8*>(qrow + g * 8);
    const short8 aq1 = *reinterpret_cast<const short8*>(qrow + 32 + g * 8);

    // diagonal-gather constants: R[lr][ki] = qe[lr][ki-lr+15] lives at
    // col-lane (d&15), register nt + (d>=16), d = n15 + 15 - lr.
    int  srcl[4];
    bool condj[4];
    #pragma unroll
    for (int j = 0; j < 4; ++j) {
        const int d = n15 + 15 - (g * 4 + j);
        srcl[j]  = (lane & 48) | (d & 15);
        condj[j] = (d >= 16);
    }

    // ---------------- pass A: row sums (no barriers) ----------------
    float lsum[4] = {0.f, 0.f, 0.f, 0.f};
    for (int t = w; t < T; t += 4) {
        const int k0 = t * 64;
        float sl[4][4];
        #pragma unroll
        for (int nt = 0; nt < 4; ++nt) {
            const ushort* krow = kh + (bhS + k0 + nt * 16 + n15) * kDH;
            f32x4 acc = {0.f, 0.f, 0.f, 0.f};
            acc = mfma16(aq0, *reinterpret_cast<const short8*>(krow + g * 8), acc);
            acc = mfma16(aq1, *reinterpret_cast<const short8*>(krow + 32 + g * 8), acc);
            #pragma unroll
            for (int j = 0; j < 4; ++j) sl[nt][j] = acc[j];
        }
        const int m_lo = 2032 + k0 - l0;
        f32x4 qe[5];
        #pragma unroll
        for (int nt = 0; nt < 5; ++nt) {
            int er = m_lo + nt * 16 + n15;
            if (er > kS - 1) er = kS - 1;        // clamped rows only feed masked elems
            const ushort* erow = eb + (size_t)er * kDH;
            f32x4 acc = {0.f, 0.f, 0.f, 0.f};
            acc = mfma16(aq0, *reinterpret_cast<const short8*>(erow + g * 8), acc);
            qe[nt] = mfma16(aq1, *reinterpret_cast<const short8*>(erow + 32 + g * 8), acc);
        }
        #pragma unroll
        for (int j = 0; j < 4; ++j) {
            float sh[5];
            #pragma unroll
            for (int q5 = 0; q5 < 5; ++q5) sh[q5] = __shfl(qe[q5][j], srcl[j]);
            const int lr = g * 4 + j;
            #pragma unroll
            for (int nt = 0; nt < 4; ++nt) {
                const float rel = condj[j] ? sh[nt + 1] : sh[nt];
                const int ki = nt * 16 + n15;
                float v = (sl[nt][j] + rel) * 0.125f;
                v = fminf(v, 60.f);
                lsum[j] += (k0 + ki <= l0 + lr) ? __expf(v) : 0.f;
            }
        }
    }
    #pragma unroll
    for (int j = 0; j < 4; ++j) {
        float s = lsum[j];
        #pragma unroll
        for (int off = 1; off < 16; off <<= 1) s += __shfl_xor(s, off);
        if (n15 == 0) lsum_s[w * 16 + g * 4 + j] = s;
    }
    __syncthreads();                             // [barrier 1] lsum exchange

    float linv[4];
    #pragma unroll
    for (int j = 0; j < 4; ++j) {
        const int r = g * 4 + j;
        linv[j] = 1.f / (lsum_s[r] + lsum_s[16 + r] + lsum_s[32 + r] + lsum_s[48 + r]);
    }

    // ---------------- pass B: emit + PV (wave-local fences only) ----------------
    f32x4 o[4];
    #pragma unroll
    for (int nt = 0; nt < 4; ++nt) o[nt] = (f32x4){0.f, 0.f, 0.f, 0.f};

    const int rr4 = lane >> 4;                   // store-phase row in group
    const int cc4 = (lane & 15) * 4;             // store-phase col

    for (int t = w; t < 32; t += 4) {
        const int k0 = t * 64;
        if (t >= T) {                            // fully masked: 256B-segment zeros
            const f32x4 z = {0.f, 0.f, 0.f, 0.f};
            #pragma unroll
            for (int i = 0; i < 4; ++i) {
                const int row = i * 4 + rr4;
                __builtin_nontemporal_store(
                    z, reinterpret_cast<f32x4*>(attn + (bhS + l0 + row) * kS + k0 + cc4));
            }
            continue;
        }
        float sl[4][4];
        #pragma unroll
        for (int nt = 0; nt < 4; ++nt) {
            const ushort* krow = kh + (bhS + k0 + nt * 16 + n15) * kDH;
            f32x4 acc = {0.f, 0.f, 0.f, 0.f};
            acc = mfma16(aq0, *reinterpret_cast<const short8*>(krow + g * 8), acc);
            acc = mfma16(aq1, *reinterpret_cast<const short8*>(krow + 32 + g * 8), acc);
            #pragma unroll
            for (int j = 0; j < 4; ++j) sl[nt][j] = acc[j];
        }
        const int m_lo = 2032 + k0 - l0;
        f32x4 qe[5];
        #pragma unroll
        for (int nt = 0; nt < 5; ++nt) {
            int er = m_lo + nt * 16 + n15;
            if (er > kS - 1) er = kS - 1;
            const ushort* erow = eb + (size_t)er * kDH;
            f32x4 acc = {0.f, 0.f, 0.f, 0.f};
            acc = mfma16(aq0, *reinterpret_cast<const short8*>(erow + g * 8), acc);
            qe[nt] = mfma16(aq1, *reinterpret_cast<const short8*>(erow + 32 + g * 8), acc);
        }
        #pragma unroll
        for (int j = 0; j < 4; ++j) {
            float sh[5];
            #pragma unroll
            for (int q5 = 0; q5 < 5; ++q5) sh[q5] = __shfl(qe[q5][j], srcl[j]);
            const int lr = g * 4 + j;
            #pragma unroll
            for (int nt = 0; nt < 4; ++nt) {
                const float rel = condj[j] ? sh[nt + 1] : sh[nt];
                const int ki = nt * 16 + n15;
                float v = (sl[nt][j] + rel) * 0.125f;
                v = fminf(v, 60.f);
                const float pe = (k0 + ki <= l0 + lr) ? __expf(v) * linv[j] : 0.f;
                Pw[lr * 68 + ki] = pe;           // ds_write_b32, 2-way banks
            }
        }
        WAVE_LDS_FENCE();                        // Pw writes -> reads

        // (a) attn stores: 4 instrs, each 4 rows x 256B contiguous segments
        #pragma unroll
        for (int i = 0; i < 4; ++i) {
            const int row = i * 4 + rr4;
            const f32x4 pv4 = *reinterpret_cast<const f32x4*>(&Pw[row * 68 + cc4]);
            __builtin_nontemporal_store(
                pv4, reinterpret_cast<f32x4*>(attn + (bhS + l0 + row) * kS + k0 + cc4));
        }
        // (b) PV A-frags: row n15, keys g*8..+8 and 32+g*8..+8
        const f32x4 plo0 = *reinterpret_cast<const f32x4*>(&Pw[n15 * 68 + g * 8]);
        const f32x4 phi0 = *reinterpret_cast<const f32x4*>(&Pw[n15 * 68 + g * 8 + 4]);
        const f32x4 plo1 = *reinterpret_cast<const f32x4*>(&Pw[n15 * 68 + 32 + g * 8]);
        const f32x4 phi1 = *reinterpret_cast<const f32x4*>(&Pw[n15 * 68 + 32 + g * 8 + 4]);
        WAVE_LDS_FENCE();                        // Pw reads retired (WAR vs next tile)

        short8 pa0, pa1;
        #pragma unroll
        for (int i = 0; i < 4; ++i) {
            pa0[i] = bfbits(plo0[i]); pa0[4 + i] = bfbits(phi0[i]);
            pa1[i] = bfbits(plo1[i]); pa1[4 + i] = bfbits(phi1[i]);
        }
        #pragma unroll
        for (int nt = 0; nt < 4; ++nt) {
            const ushort* vrow = vt + ((size_t)bh * kDH + nt * 16 + n15) * kS + k0;
            o[nt] = mfma16(pa0, *reinterpret_cast<const short8*>(vrow + g * 8), o[nt]);
            o[nt] = mfma16(pa1, *reinterpret_cast<const short8*>(vrow + 32 + g * 8), o[nt]);
        }
    }

    // ---------------- O combine (O_s aliases Pw region) ----------------
    __syncthreads();                             // [barrier 2] all Pw reads done
    float* O_s = (float*)smem;                   // 4 waves x 16x64 f32 = 16 KiB
    #pragma unroll
    for (int nt = 0; nt < 4; ++nt)
        #pragma unroll
        for (int j = 0; j < 4; ++j)
            O_s[w * 1024 + (g * 4 + j) * 64 + nt * 16 + n15] = o[nt][j];
    __syncthreads();                             // [barrier 3]

    const int b = bh >> 3, h = bh & 7;
    #pragma unroll
    for (int i = tid; i < 1024; i += 256) {
        const int r = i >> 6, c = i & 63;
        const float acc = O_s[i] + O_s[1024 + i] + O_s[2048 + i] + O_s[3072 + i];
        ohb[((size_t)b * kS + l0 + r) * kD + h * kDH + c] = (ushort)bfbits(acc);
    }
}

// ---------------------------------------------------------------------------
extern "C" void kernel_launch(void* const* d_in, const int* in_sizes, int n_in,
                              void* d_out, int out_size, void* d_ws, size_t ws_size,
                              hipStream_t stream)
{
    const float* q_in = (const float*)d_in[0];
    const float* k_in = (const float*)d_in[1];
    const float* v_in = (const float*)d_in[2];
    const float* Wq = (const float*)d_in[4];
    const float* bq = (const float*)d_in[5];
    const float* Wk = (const float*)d_in[6];
    const float* bk = (const float*)d_in[7];
    const float* Wv = (const float*)d_in[8];
    const float* bv = (const float*)d_in[9];
    const float* Wo = (const float*)d_in[10];
    const float* bo = (const float*)d_in[11];
    const float* E  = (const float*)d_in[12];

    float* out  = (float*)d_out;                          // (B,S,D)
    float* attn = (float*)d_out + (size_t)kB * kS * kD;   // (B,H,S,S)

    // workspace: all bf16 (~31.7 MB)
    ushort* qh  = (ushort*)d_ws;          // (B,H,S,DH)
    ushort* kh  = qh  + 2097152;          // (B,H,S,DH)
    ushort* vt  = kh  + 2097152;          // (B,H,DH,S)
    ushort* ohb = vt  + 2097152;          // (B,S,D)
    ushort* qb  = ohb + 2097152;          // (B,S,D) inputs in bf16
    ushort* kb  = qb  + 2097152;
    ushort* vb  = kb  + 2097152;
    ushort* eb  = vb  + 2097152;          // (2048,64)
    ushort* Wqt = eb  + 131072;           // col-major 512x512
    ushort* Wkt = Wqt + 262144;
    ushort* Wvt = Wkt + 262144;
    ushort* Wot = Wvt + 262144;

    convw_kernel<<<dim3(8, 8, 5), 256, 0, stream>>>(Wq, Wk, Wv, Wo, E,
                                                    Wqt, Wkt, Wvt, Wot, eb);
    cvta_kernel<<<dim3(1024, 1, 3), 256, 0, stream>>>(q_in, k_in, v_in, qb, kb, vb);
    gemm_qkv_kernel<<<dim3(64, 16, 3), 256, 0, stream>>>(qb, kb, vb,
                                                         Wqt, Wkt, Wvt,
                                                         bq, bk, bv, qh, kh, vt);
    attn_fused_kernel<<<dim3(16, 128), 256, 0, stream>>>(qh, kh, vt, eb, attn, ohb);
    gemm_o_kernel<<<dim3(64, 16), 256, 0, stream>>>(ohb, Wot, bo, out);
}

// Round 13
// 223.891 us; speedup vs baseline: 1.5187x; 1.4782x over previous
//
#include <hip/hip_runtime.h>
#include <hip/hip_bf16.h>

// RelativeGlobalAttention: B=2, S=2048, D=512, H=8, DH=64, MAX_SEQ=2048
// out0 = attention output (B,S,D); out1 = attn probs (B,H,S,S); concatenated.
//
// Identity: srel[l,k] = q[l].E[2047-l+k] for k<=l, else 0.
// logits = (QK^T + srel)/8; causal mask => masked probs exactly 0.
// No-max softmax: exp(v)/sum(exp(v)) == reference softmax up to fp32 rounding.
//
// R13 theory: the wall since R2 is address divergence — every K/E/V fragment
// load touches 16 cache lines (16 lanes x 128B stride, 16B each). Model fits
// R1 (64 lines/instr -> 2.3ms) and R10 (16 lines/instr -> ~197us). Fix =
// canonical LDS staging: block cooperatively stages K/E/V tiles with DENSE
// coalesced loads into XOR-swizzled LDS; fragments come from LDS. Tile work
// split by wave (ki-quadrant for scores, dh-quadrant for PV -> wave-private O).

namespace {
constexpr int kS  = 2048;
constexpr int kD  = 512;
constexpr int kH  = 8;
constexpr int kDH = 64;
constexpr int kB  = 2;

typedef __attribute__((ext_vector_type(8))) short short8;   // 8 x bf16
typedef __attribute__((ext_vector_type(4))) float f32x4;

// LDS layout (bytes)
constexpr int kKl = 0;        // K tile: 64 rows x 128B, swizzled
constexpr int kVl = 8192;     // V^T tile: 64 dh-rows x 128B, swizzled
constexpr int kEl = 16384;    // E window: 80 rows x 128B, swizzled
constexpr int kPf = 26624;    // P: 16 x 68 f32
constexpr int kLs = 30976;    // lsum_s: 64 f32
}

__device__ __forceinline__ f32x4 mfma16(short8 a, short8 b, f32x4 c) {
    return __builtin_amdgcn_mfma_f32_16x16x32_bf16(a, b, c, 0, 0, 0);
}

__device__ __forceinline__ short bfbits(float f) {
    __hip_bfloat16 h = __float2bfloat16(f);
    return *reinterpret_cast<short*>(&h);
}

// ---------------------------------------------------------------------------
// conv: W (512x512 fp32 row-major) -> Wt (bf16 col-major [c][k]) x4; E -> bf16
// ---------------------------------------------------------------------------
__global__ __launch_bounds__(256)
void convw_kernel(const float* __restrict__ Wq, const float* __restrict__ Wk,
                  const float* __restrict__ Wv, const float* __restrict__ Wo,
                  const float* __restrict__ E,
                  ushort* __restrict__ Wqt, ushort* __restrict__ Wkt,
                  ushort* __restrict__ Wvt, ushort* __restrict__ Wot,
                  ushort* __restrict__ eb)
{
    const int z = blockIdx.z;
    const int tid = threadIdx.x;
    if (z == 4) {   // E: 2048x64 = 131072 elems
        const int idx = ((blockIdx.y * 8 + blockIdx.x) * 256 + tid) * 8;
        const float4 x = *reinterpret_cast<const float4*>(E + idx);
        const float4 y = *reinterpret_cast<const float4*>(E + idx + 4);
        short8 r;
        r[0] = bfbits(x.x); r[1] = bfbits(x.y); r[2] = bfbits(x.z); r[3] = bfbits(x.w);
        r[4] = bfbits(y.x); r[5] = bfbits(y.y); r[6] = bfbits(y.z); r[7] = bfbits(y.w);
        *reinterpret_cast<short8*>(eb + idx) = r;
        return;
    }
    const float* W = (z == 0) ? Wq : (z == 1) ? Wk : (z == 2) ? Wv : Wo;
    ushort* Wt = (z == 0) ? Wqt : (z == 1) ? Wkt : (z == 2) ? Wvt : Wot;

    __shared__ float Ws[64][65];
    const int k0 = blockIdx.x * 64;
    const int c0 = blockIdx.y * 64;
    const int cc = tid & 63;
    const int rq = tid >> 6;
    #pragma unroll
    for (int ii = 0; ii < 16; ++ii) {
        const int r = ii * 4 + rq;
        Ws[r][cc] = W[(size_t)(k0 + r) * kD + c0 + cc];
    }
    __syncthreads();
    #pragma unroll
    for (int ii = 0; ii < 16; ++ii) {
        const int r = ii * 4 + rq;
        Wt[(size_t)(c0 + r) * kD + k0 + cc] = (ushort)bfbits(Ws[cc][r]);
    }
}

// q_in/k_in/v_in fp32 (B,S,D) -> bf16
__global__ __launch_bounds__(256)
void cvta_kernel(const float* __restrict__ q, const float* __restrict__ k,
                 const float* __restrict__ v,
                 ushort* __restrict__ qb, ushort* __restrict__ kb,
                 ushort* __restrict__ vb)
{
    const int z = blockIdx.z;
    const float* src = (z == 0) ? q : (z == 1) ? k : v;
    ushort* dst = (z == 0) ? qb : (z == 1) ? kb : vb;
    const int idx = (blockIdx.x * 256 + threadIdx.x) * 8;
    const float4 x = *reinterpret_cast<const float4*>(src + idx);
    const float4 y = *reinterpret_cast<const float4*>(src + idx + 4);
    short8 r;
    r[0] = bfbits(x.x); r[1] = bfbits(x.y); r[2] = bfbits(x.z); r[3] = bfbits(x.w);
    r[4] = bfbits(y.x); r[5] = bfbits(y.y); r[6] = bfbits(y.z); r[7] = bfbits(y.w);
    *reinterpret_cast<short8*>(dst + idx) = r;
}

// ---------------------------------------------------------------------------
// MFMA GEMM core (R10 form, unchanged)
// ---------------------------------------------------------------------------
template<int MODE>
__device__ __forceinline__
void gemm_core(const ushort* __restrict__ A, const ushort* __restrict__ Wt,
               const float* __restrict__ bias, void* __restrict__ out)
{
    const int tid  = threadIdx.x;
    const int w    = tid >> 6;
    const int lane = tid & 63;
    const int g    = lane >> 4;
    const int n15  = lane & 15;
    const int r0   = blockIdx.x * 64 + w * 16;
    const int c0   = blockIdx.y * 32;

    f32x4 acc0 = {0.f, 0.f, 0.f, 0.f};
    f32x4 acc1 = {0.f, 0.f, 0.f, 0.f};
    const ushort* arow = A  + (size_t)(r0 + n15) * kD + g * 8;
    const ushort* b0p  = Wt + (size_t)(c0 + n15) * kD + g * 8;
    const ushort* b1p  = Wt + (size_t)(c0 + 16 + n15) * kD + g * 8;

    #pragma unroll 4
    for (int k0 = 0; k0 < kD; k0 += 32) {
        const short8 a  = *reinterpret_cast<const short8*>(arow + k0);
        const short8 b0 = *reinterpret_cast<const short8*>(b0p + k0);
        const short8 b1 = *reinterpret_cast<const short8*>(b1p + k0);
        acc0 = mfma16(a, b0, acc0);
        acc1 = mfma16(a, b1, acc1);
    }

    #pragma unroll
    for (int cg = 0; cg < 2; ++cg) {
        const f32x4 acc = cg ? acc1 : acc0;
        const int c = c0 + cg * 16 + n15;
        const float bb = bias[c];
        const int h = c >> 6, d = c & (kDH - 1);
        #pragma unroll
        for (int j = 0; j < 4; ++j) {
            const int r = r0 + g * 4 + j;
            const float val = acc[j] + bb;
            const int b = r >> 11, s2 = r & (kS - 1);
            if (MODE == 0) {
                ((float*)out)[(size_t)r * kD + c] = val;
            } else if (MODE == 1) {
                ((ushort*)out)[((size_t)(b * kH + h) * kS + s2) * kDH + d] = (ushort)bfbits(val);
            } else {
                ((ushort*)out)[((size_t)(b * kH + h) * kDH + d) * kS + s2] = (ushort)bfbits(val);
            }
        }
    }
}

__global__ __launch_bounds__(256)
void gemm_qkv_kernel(const ushort* __restrict__ qb, const ushort* __restrict__ kb,
                     const ushort* __restrict__ vb,
                     const ushort* __restrict__ Wqt, const ushort* __restrict__ Wkt,
                     const ushort* __restrict__ Wvt,
                     const float* __restrict__ bq, const float* __restrict__ bk,
                     const float* __restrict__ bv,
                     ushort* __restrict__ qh, ushort* __restrict__ kh,
                     ushort* __restrict__ vt)
{
    const int z = blockIdx.z;
    const ushort* A    = (z == 0) ? qb  : (z == 1) ? kb  : vb;
    const ushort* Wt   = (z == 0) ? Wqt : (z == 1) ? Wkt : Wvt;
    const float*  bias = (z == 0) ? bq  : (z == 1) ? bk  : bv;
    void*         out  = (z == 0) ? (void*)qh : (z == 1) ? (void*)kh : (void*)vt;
    if (z == 2) gemm_core<2>(A, Wt, bias, out);
    else        gemm_core<1>(A, Wt, bias, out);
}

__global__ __launch_bounds__(256)
void gemm_o_kernel(const ushort* __restrict__ ohb, const ushort* __restrict__ Wot,
                   const float* __restrict__ bo, float* __restrict__ out)
{
    gemm_core<0>(ohb, Wot, bo, out);
}

// ---------------------------------------------------------------------------
// Fused attention, LDS-staged (R13). Block = (bh, 16-row strip), 4 waves.
// Per tile: block stages K (64x128B), E (80x128B), V^T (64x128B) into
// XOR-swizzled LDS via dense coalesced loads; wave w computes score
// ki-quadrant w and PV dh-quadrant w (O wave-private). P via block-shared
// [16][68] f32 LDS; attn stored row-major (1 f32x4/thread/tile, nt).
// Barriers are uniform (t/T block-uniform). grid (16,128) x 256.
// ---------------------------------------------------------------------------
__global__ __launch_bounds__(256, 4)
void attn_fused_kernel(const ushort* __restrict__ qh, const ushort* __restrict__ khp,
                       const ushort* __restrict__ vt, const ushort* __restrict__ eb,
                       float* __restrict__ attn, ushort* __restrict__ ohb)
{
    __shared__ __align__(16) char smem[31232];
    float* Pf     = (float*)(smem + kPf);
    float* lsum_s = (float*)(smem + kLs);

    const int bh    = blockIdx.x;
    const int strip = 127 - (int)blockIdx.y;     // big-work-first
    const int l0    = strip * 16;
    const int tid   = threadIdx.x;
    const int w     = tid >> 6;
    const int lane  = tid & 63;
    const int g     = lane >> 4;
    const int n15   = lane & 15;
    const size_t bhS = (size_t)bh * kS;

    const int T = ((l0 + 15) >> 6) + 1;          // causal 64-wide tiles

    // Q fragments (A-operand), once per block
    const ushort* qrow = qh + (bhS + l0 + n15) * kDH;
    const short8 aq0 = *reinterpret_cast<const short8*>(qrow + g * 8);
    const short8 aq1 = *reinterpret_cast<const short8*>(qrow + 32 + g * 8);

    // diagonal-gather constants: rel for (lr, ki=w*16+n15) sits in this
    // wave's qe[d>=16] at col-lane d&15, row-group g; d = n15 + 15 - lr.
    int  srcl[4];
    bool condj[4];
    #pragma unroll
    for (int j = 0; j < 4; ++j) {
        const int d = n15 + 15 - (g * 4 + j);
        srcl[j]  = (lane & 48) | (d & 15);
        condj[j] = (d >= 16);
    }

    const int rW = w * 16 + n15;                 // this wave's K/V LDS row
    const int mS = (n15 & 7) << 4;               // fragment-read swizzle mask
    const int b0 = (g * 16) ^ mS;                // frag bytes (lo 32 keys/dims)
    const int b1 = (64 + g * 16) ^ mS;           // frag bytes (hi 32)

    // ---------------- pass A: row sums ----------------
    float lsum[4] = {0.f, 0.f, 0.f, 0.f};
    for (int t = 0; t < T; ++t) {
        const int k0 = t * 64;
        const int m_lo = 2032 + k0 - l0;
        __syncthreads();                         // prior tile's LDS reads done
        // stage K: 512 x 16B chunks, dense
        for (int c = tid; c < 512; c += 256) {
            const int row = c >> 3, bi = (c & 7) * 16;
            const short8 v = *reinterpret_cast<const short8*>(
                khp + (bhS + k0 + row) * kDH + (c & 7) * 8);
            *reinterpret_cast<short8*>(smem + kKl + row * 128 + (bi ^ ((row & 7) << 4))) = v;
        }
        // stage E window: 640 chunks (80 rows), clamped
        for (int c = tid; c < 640; c += 256) {
            const int row = c >> 3, bi = (c & 7) * 16;
            const int er = min(m_lo + row, kS - 1);   // clamped rows feed masked elems only
            const short8 v = *reinterpret_cast<const short8*>(
                eb + (size_t)er * kDH + (c & 7) * 8);
            *reinterpret_cast<short8*>(smem + kEl + row * 128 + (bi ^ ((row & 7) << 4))) = v;
        }
        __syncthreads();                         // staged data visible

        // scores: wave w owns ki-quadrant w
        f32x4 s4 = {0.f, 0.f, 0.f, 0.f};
        s4 = mfma16(aq0, *reinterpret_cast<const short8*>(smem + kKl + rW * 128 + b0), s4);
        s4 = mfma16(aq1, *reinterpret_cast<const short8*>(smem + kKl + rW * 128 + b1), s4);
        f32x4 qe2[2];
        #pragma unroll
        for (int q2 = 0; q2 < 2; ++q2) {
            const int rE = w * 16 + q2 * 16 + n15;
            f32x4 acc = {0.f, 0.f, 0.f, 0.f};
            acc = mfma16(aq0, *reinterpret_cast<const short8*>(smem + kEl + rE * 128 + b0), acc);
            qe2[q2] = mfma16(aq1, *reinterpret_cast<const short8*>(smem + kEl + rE * 128 + b1), acc);
        }
        #pragma unroll
        for (int j = 0; j < 4; ++j) {
            const float sh0 = __shfl(qe2[0][j], srcl[j]);
            const float sh1 = __shfl(qe2[1][j], srcl[j]);
            const float rel = condj[j] ? sh1 : sh0;
            float v = (s4[j] + rel) * 0.125f;
            v = fminf(v, 60.f);
            const bool keep = (k0 + w * 16 + n15 <= l0 + g * 4 + j);
            lsum[j] += keep ? __expf(v) : 0.f;
        }
    }
    #pragma unroll
    for (int j = 0; j < 4; ++j) {
        float s = lsum[j];
        #pragma unroll
        for (int off = 1; off < 16; off <<= 1) s += __shfl_xor(s, off);
        if (n15 == 0) lsum_s[w * 16 + g * 4 + j] = s;
    }
    __syncthreads();                             // lsum exchange

    float linv[4];
    #pragma unroll
    for (int j = 0; j < 4; ++j) {
        const int r = g * 4 + j;
        linv[j] = 1.f / (lsum_s[r] + lsum_s[16 + r] + lsum_s[32 + r] + lsum_s[48 + r]);
    }

    // ---------------- pass B: emit + PV ----------------
    f32x4 o = {0.f, 0.f, 0.f, 0.f};              // wave-private dh-quadrant w
    const int srow = tid >> 4;                   // store row 0..15
    const int scol = (tid & 15) * 4;             // store col (f32)

    for (int t = 0; t < 32; ++t) {
        const int k0 = t * 64;
        if (t >= T) {                            // fully masked: 1 f32x4/thread
            const f32x4 z = {0.f, 0.f, 0.f, 0.f};
            __builtin_nontemporal_store(
                z, reinterpret_cast<f32x4*>(attn + (bhS + l0 + srow) * kS + k0 + scol));
            continue;
        }
        const int m_lo = 2032 + k0 - l0;
        __syncthreads();                         // prior tile's LDS reads done
        for (int c = tid; c < 512; c += 256) {   // stage K
            const int row = c >> 3, bi = (c & 7) * 16;
            const short8 v = *reinterpret_cast<const short8*>(
                khp + (bhS + k0 + row) * kDH + (c & 7) * 8);
            *reinterpret_cast<short8*>(smem + kKl + row * 128 + (bi ^ ((row & 7) << 4))) = v;
        }
        for (int c = tid; c < 512; c += 256) {   // stage V^T
            const int row = c >> 3, bi = (c & 7) * 16;
            const short8 v = *reinterpret_cast<const short8*>(
                vt + ((size_t)bh * kDH + row) * kS + k0 + (c & 7) * 8);
            *reinterpret_cast<short8*>(smem + kVl + row * 128 + (bi ^ ((row & 7) << 4))) = v;
        }
        for (int c = tid; c < 640; c += 256) {   // stage E window
            const int row = c >> 3, bi = (c & 7) * 16;
            const int er = min(m_lo + row, kS - 1);
            const short8 v = *reinterpret_cast<const short8*>(
                eb + (size_t)er * kDH + (c & 7) * 8);
            *reinterpret_cast<short8*>(smem + kEl + row * 128 + (bi ^ ((row & 7) << 4))) = v;
        }
        __syncthreads();                         // staged data visible

        f32x4 s4 = {0.f, 0.f, 0.f, 0.f};
        s4 = mfma16(aq0, *reinterpret_cast<const short8*>(smem + kKl + rW * 128 + b0), s4);
        s4 = mfma16(aq1, *reinterpret_cast<const short8*>(smem + kKl + rW * 128 + b1), s4);
        f32x4 qe2[2];
        #pragma unroll
        for (int q2 = 0; q2 < 2; ++q2) {
            const int rE = w * 16 + q2 * 16 + n15;
            f32x4 acc = {0.f, 0.f, 0.f, 0.f};
            acc = mfma16(aq0, *reinterpret_cast<const short8*>(smem + kEl + rE * 128 + b0), acc);
            qe2[q2] = mfma16(aq1, *reinterpret_cast<const short8*>(smem + kEl + rE * 128 + b1), acc);
        }
        #pragma unroll
        for (int j = 0; j < 4; ++j) {
            const float sh0 = __shfl(qe2[0][j], srcl[j]);
            const float sh1 = __shfl(qe2[1][j], srcl[j]);
            const float rel = condj[j] ? sh1 : sh0;
            float v = (s4[j] + rel) * 0.125f;
            v = fminf(v, 60.f);
            const bool keep = (k0 + w * 16 + n15 <= l0 + g * 4 + j);
            const float pe = keep ? __expf(v) * linv[j] : 0.f;
            Pf[(g * 4 + j) * 68 + w * 16 + n15] = pe;
        }
        __syncthreads();                         // P visible

        // attn store: 1 f32x4 per thread, 256B-contiguous row segments
        const f32x4 pv4 = *reinterpret_cast<const f32x4*>(Pf + srow * 68 + scol);
        __builtin_nontemporal_store(
            pv4, reinterpret_cast<f32x4*>(attn + (bhS + l0 + srow) * kS + k0 + scol));

        // PV: wave w owns dh-quadrant w; A-frags from P, B-frags from V LDS
        const f32x4 plo0 = *reinterpret_cast<const f32x4*>(Pf + n15 * 68 + g * 8);
        const f32x4 phi0 = *reinterpret_cast<const f32x4*>(Pf + n15 * 68 + g * 8 + 4);
        const f32x4 plo1 = *reinterpret_cast<const f32x4*>(Pf + n15 * 68 + 32 + g * 8);
        const f32x4 phi1 = *reinterpret_cast<const f32x4*>(Pf + n15 * 68 + 32 + g * 8 + 4);
        short8 pa0, pa1;
        #pragma unroll
        for (int i = 0; i < 4; ++i) {
            pa0[i] = bfbits(plo0[i]); pa0[4 + i] = bfbits(phi0[i]);
            pa1[i] = bfbits(plo1[i]); pa1[4 + i] = bfbits(phi1[i]);
        }
        o = mfma16(pa0, *reinterpret_cast<const short8*>(smem + kVl + rW * 128 + b0), o);
        o = mfma16(pa1, *reinterpret_cast<const short8*>(smem + kVl + rW * 128 + b1), o);
        // next iteration's leading __syncthreads() protects P/K/V/E reuse
    }

    // epilogue: wave-private O -> ohb (B,S,D) bf16
    const int b = bh >> 3, h = bh & 7;
    #pragma unroll
    for (int j = 0; j < 4; ++j)
        ohb[((size_t)b * kS + l0 + g * 4 + j) * kD + h * kDH + w * 16 + n15] =
            (ushort)bfbits(o[j]);
}

// ---------------------------------------------------------------------------
extern "C" void kernel_launch(void* const* d_in, const int* in_sizes, int n_in,
                              void* d_out, int out_size, void* d_ws, size_t ws_size,
                              hipStream_t stream)
{
    const float* q_in = (const float*)d_in[0];
    const float* k_in = (const float*)d_in[1];
    const float* v_in = (const float*)d_in[2];
    const float* Wq = (const float*)d_in[4];
    const float* bq = (const float*)d_in[5];
    const float* Wk = (const float*)d_in[6];
    const float* bk = (const float*)d_in[7];
    const float* Wv = (const float*)d_in[8];
    const float* bv = (const float*)d_in[9];
    const float* Wo = (const float*)d_in[10];
    const float* bo = (const float*)d_in[11];
    const float* E  = (const float*)d_in[12];

    float* out  = (float*)d_out;                          // (B,S,D)
    float* attn = (float*)d_out + (size_t)kB * kS * kD;   // (B,H,S,S)

    // workspace: all bf16 (~31.7 MB)
    ushort* qh  = (ushort*)d_ws;          // (B,H,S,DH)
    ushort* kh  = qh  + 2097152;          // (B,H,S,DH)
    ushort* vt  = kh  + 2097152;          // (B,H,DH,S)
    ushort* ohb = vt  + 2097152;          // (B,S,D)
    ushort* qb  = ohb + 2097152;          // (B,S,D) inputs in bf16
    ushort* kb  = qb  + 2097152;
    ushort* vb  = kb  + 2097152;
    ushort* eb  = vb  + 2097152;          // (2048,64)
    ushort* Wqt = eb  + 131072;           // col-major 512x512
    ushort* Wkt = Wqt + 262144;
    ushort* Wvt = Wkt + 262144;
    ushort* Wot = Wvt + 262144;

    convw_kernel<<<dim3(8, 8, 5), 256, 0, stream>>>(Wq, Wk, Wv, Wo, E,
                                                    Wqt, Wkt, Wvt, Wot, eb);
    cvta_kernel<<<dim3(1024, 1, 3), 256, 0, stream>>>(q_in, k_in, v_in, qb, kb, vb);
    gemm_qkv_kernel<<<dim3(64, 16, 3), 256, 0, stream>>>(qb, kb, vb,
                                                         Wqt, Wkt, Wvt,
                                                         bq, bk, bv, qh, kh, vt);
    attn_fused_kernel<<<dim3(16, 128), 256, 0, stream>>>(qh, kh, vt, eb, attn, ohb);
    gemm_o_kernel<<<dim3(64, 16), 256, 0, stream>>>(ohb, Wot, bo, out);
}

// Round 14
// 222.680 us; speedup vs baseline: 1.5269x; 1.0054x over previous
//
#include <hip/hip_runtime.h>
#include <hip/hip_bf16.h>

// RelativeGlobalAttention: B=2, S=2048, D=512, H=8, DH=64, MAX_SEQ=2048
// out0 = attention output (B,S,D); out1 = attn probs (B,H,S,S); concatenated.
//
// Identity: srel[l,k] = q[l].E[2047-l+k] for k<=l, else 0.
// logits = (QK^T + srel)/8; causal mask => masked probs exactly 0.
// No-max softmax: exp(v)/sum(exp(v)) == reference softmax up to fp32 rounding.
//
// R13 theory: the wall since R2 is address divergence — every K/E/V fragment
// load touches 16 cache lines (16 lanes x 128B stride, 16B each). Model fits
// R1 (64 lines/instr -> 2.3ms) and R10 (16 lines/instr -> ~197us). Fix =
// canonical LDS staging: block cooperatively stages K/E/V tiles with DENSE
// coalesced loads into XOR-swizzled LDS; fragments come from LDS. Tile work
// split by wave (ki-quadrant for scores, dh-quadrant for PV -> wave-private O).

namespace {
constexpr int kS  = 2048;
constexpr int kD  = 512;
constexpr int kH  = 8;
constexpr int kDH = 64;
constexpr int kB  = 2;

typedef __attribute__((ext_vector_type(8))) short short8;   // 8 x bf16
typedef __attribute__((ext_vector_type(4))) float f32x4;

// LDS layout (bytes)
constexpr int kKl = 0;        // K tile: 64 rows x 128B, swizzled
constexpr int kVl = 8192;     // V^T tile: 64 dh-rows x 128B, swizzled
constexpr int kEl = 16384;    // E window: 80 rows x 128B, swizzled
constexpr int kPf = 26624;    // P: 16 x 68 f32
constexpr int kLs = 30976;    // lsum_s: 64 f32
}

__device__ __forceinline__ f32x4 mfma16(short8 a, short8 b, f32x4 c) {
    return __builtin_amdgcn_mfma_f32_16x16x32_bf16(a, b, c, 0, 0, 0);
}

__device__ __forceinline__ short bfbits(float f) {
    __hip_bfloat16 h = __float2bfloat16(f);
    return *reinterpret_cast<short*>(&h);
}

// ---------------------------------------------------------------------------
// conv: W (512x512 fp32 row-major) -> Wt (bf16 col-major [c][k]) x4; E -> bf16
// ---------------------------------------------------------------------------
__global__ __launch_bounds__(256)
void convw_kernel(const float* __restrict__ Wq, const float* __restrict__ Wk,
                  const float* __restrict__ Wv, const float* __restrict__ Wo,
                  const float* __restrict__ E,
                  ushort* __restrict__ Wqt, ushort* __restrict__ Wkt,
                  ushort* __restrict__ Wvt, ushort* __restrict__ Wot,
                  ushort* __restrict__ eb)
{
    const int z = blockIdx.z;
    const int tid = threadIdx.x;
    if (z == 4) {   // E: 2048x64 = 131072 elems
        const int idx = ((blockIdx.y * 8 + blockIdx.x) * 256 + tid) * 8;
        const float4 x = *reinterpret_cast<const float4*>(E + idx);
        const float4 y = *reinterpret_cast<const float4*>(E + idx + 4);
        short8 r;
        r[0] = bfbits(x.x); r[1] = bfbits(x.y); r[2] = bfbits(x.z); r[3] = bfbits(x.w);
        r[4] = bfbits(y.x); r[5] = bfbits(y.y); r[6] = bfbits(y.z); r[7] = bfbits(y.w);
        *reinterpret_cast<short8*>(eb + idx) = r;
        return;
    }
    const float* W = (z == 0) ? Wq : (z == 1) ? Wk : (z == 2) ? Wv : Wo;
    ushort* Wt = (z == 0) ? Wqt : (z == 1) ? Wkt : (z == 2) ? Wvt : Wot;

    __shared__ float Ws[64][65];
    const int k0 = blockIdx.x * 64;
    const int c0 = blockIdx.y * 64;
    const int cc = tid & 63;
    const int rq = tid >> 6;
    #pragma unroll
    for (int ii = 0; ii < 16; ++ii) {
        const int r = ii * 4 + rq;
        Ws[r][cc] = W[(size_t)(k0 + r) * kD + c0 + cc];
    }
    __syncthreads();
    #pragma unroll
    for (int ii = 0; ii < 16; ++ii) {
        const int r = ii * 4 + rq;
        Wt[(size_t)(c0 + r) * kD + k0 + cc] = (ushort)bfbits(Ws[cc][r]);
    }
}

// q_in/k_in/v_in fp32 (B,S,D) -> bf16
__global__ __launch_bounds__(256)
void cvta_kernel(const float* __restrict__ q, const float* __restrict__ k,
                 const float* __restrict__ v,
                 ushort* __restrict__ qb, ushort* __restrict__ kb,
                 ushort* __restrict__ vb)
{
    const int z = blockIdx.z;
    const float* src = (z == 0) ? q : (z == 1) ? k : v;
    ushort* dst = (z == 0) ? qb : (z == 1) ? kb : vb;
    const int idx = (blockIdx.x * 256 + threadIdx.x) * 8;
    const float4 x = *reinterpret_cast<const float4*>(src + idx);
    const float4 y = *reinterpret_cast<const float4*>(src + idx + 4);
    short8 r;
    r[0] = bfbits(x.x); r[1] = bfbits(x.y); r[2] = bfbits(x.z); r[3] = bfbits(x.w);
    r[4] = bfbits(y.x); r[5] = bfbits(y.y); r[6] = bfbits(y.z); r[7] = bfbits(y.w);
    *reinterpret_cast<short8*>(dst + idx) = r;
}

// ---------------------------------------------------------------------------
// MFMA GEMM core (R10 form, unchanged)
// ---------------------------------------------------------------------------
template<int MODE>
__device__ __forceinline__
void gemm_core(const ushort* __restrict__ A, const ushort* __restrict__ Wt,
               const float* __restrict__ bias, void* __restrict__ out)
{
    const int tid  = threadIdx.x;
    const int w    = tid >> 6;
    const int lane = tid & 63;
    const int g    = lane >> 4;
    const int n15  = lane & 15;
    const int r0   = blockIdx.x * 64 + w * 16;
    const int c0   = blockIdx.y * 32;

    f32x4 acc0 = {0.f, 0.f, 0.f, 0.f};
    f32x4 acc1 = {0.f, 0.f, 0.f, 0.f};
    const ushort* arow = A  + (size_t)(r0 + n15) * kD + g * 8;
    const ushort* b0p  = Wt + (size_t)(c0 + n15) * kD + g * 8;
    const ushort* b1p  = Wt + (size_t)(c0 + 16 + n15) * kD + g * 8;

    #pragma unroll 4
    for (int k0 = 0; k0 < kD; k0 += 32) {
        const short8 a  = *reinterpret_cast<const short8*>(arow + k0);
        const short8 b0 = *reinterpret_cast<const short8*>(b0p + k0);
        const short8 b1 = *reinterpret_cast<const short8*>(b1p + k0);
        acc0 = mfma16(a, b0, acc0);
        acc1 = mfma16(a, b1, acc1);
    }

    #pragma unroll
    for (int cg = 0; cg < 2; ++cg) {
        const f32x4 acc = cg ? acc1 : acc0;
        const int c = c0 + cg * 16 + n15;
        const float bb = bias[c];
        const int h = c >> 6, d = c & (kDH - 1);
        #pragma unroll
        for (int j = 0; j < 4; ++j) {
            const int r = r0 + g * 4 + j;
            const float val = acc[j] + bb;
            const int b = r >> 11, s2 = r & (kS - 1);
            if (MODE == 0) {
                ((float*)out)[(size_t)r * kD + c] = val;
            } else if (MODE == 1) {
                ((ushort*)out)[((size_t)(b * kH + h) * kS + s2) * kDH + d] = (ushort)bfbits(val);
            } else {
                ((ushort*)out)[((size_t)(b * kH + h) * kDH + d) * kS + s2] = (ushort)bfbits(val);
            }
        }
    }
}

__global__ __launch_bounds__(256)
void gemm_qkv_kernel(const ushort* __restrict__ qb, const ushort* __restrict__ kb,
                     const ushort* __restrict__ vb,
                     const ushort* __restrict__ Wqt, const ushort* __restrict__ Wkt,
                     const ushort* __restrict__ Wvt,
                     const float* __restrict__ bq, const float* __restrict__ bk,
                     const float* __restrict__ bv,
                     ushort* __restrict__ qh, ushort* __restrict__ kh,
                     ushort* __restrict__ vt)
{
    const int z = blockIdx.z;
    const ushort* A    = (z == 0) ? qb  : (z == 1) ? kb  : vb;
    const ushort* Wt   = (z == 0) ? Wqt : (z == 1) ? Wkt : Wvt;
    const float*  bias = (z == 0) ? bq  : (z == 1) ? bk  : bv;
    void*         out  = (z == 0) ? (void*)qh : (z == 1) ? (void*)kh : (void*)vt;
    if (z == 2) gemm_core<2>(A, Wt, bias, out);
    else        gemm_core<1>(A, Wt, bias, out);
}

__global__ __launch_bounds__(256)
void gemm_o_kernel(const ushort* __restrict__ ohb, const ushort* __restrict__ Wot,
                   const float* __restrict__ bo, float* __restrict__ out)
{
    gemm_core<0>(ohb, Wot, bo, out);
}

// ---------------------------------------------------------------------------
// Fused attention, LDS-staged (R13). Block = (bh, 16-row strip), 4 waves.
// Per tile: block stages K (64x128B), E (80x128B), V^T (64x128B) into
// XOR-swizzled LDS via dense coalesced loads; wave w computes score
// ki-quadrant w and PV dh-quadrant w (O wave-private). P via block-shared
// [16][68] f32 LDS; attn stored row-major (1 f32x4/thread/tile, nt).
// Barriers are uniform (t/T block-uniform). grid (16,128) x 256.
// ---------------------------------------------------------------------------
__global__ __launch_bounds__(256, 4)
void attn_fused_kernel(const ushort* __restrict__ qh, const ushort* __restrict__ khp,
                       const ushort* __restrict__ vt, const ushort* __restrict__ eb,
                       float* __restrict__ attn, ushort* __restrict__ ohb)
{
    __shared__ __align__(16) char smem[31232];
    float* Pf     = (float*)(smem + kPf);
    float* lsum_s = (float*)(smem + kLs);

    const int bh    = blockIdx.x;
    const int strip = 127 - (int)blockIdx.y;     // big-work-first
    const int l0    = strip * 16;
    const int tid   = threadIdx.x;
    const int w     = tid >> 6;
    const int lane  = tid & 63;
    const int g     = lane >> 4;
    const int n15   = lane & 15;
    const size_t bhS = (size_t)bh * kS;

    const int T = ((l0 + 15) >> 6) + 1;          // causal 64-wide tiles

    // Q fragments (A-operand), once per block
    const ushort* qrow = qh + (bhS + l0 + n15) * kDH;
    const short8 aq0 = *reinterpret_cast<const short8*>(qrow + g * 8);
    const short8 aq1 = *reinterpret_cast<const short8*>(qrow + 32 + g * 8);

    // diagonal-gather constants: rel for (lr, ki=w*16+n15) sits in this
    // wave's qe[d>=16] at col-lane d&15, row-group g; d = n15 + 15 - lr.
    int  srcl[4];
    bool condj[4];
    #pragma unroll
    for (int j = 0; j < 4; ++j) {
        const int d = n15 + 15 - (g * 4 + j);
        srcl[j]  = (lane & 48) | (d & 15);
        condj[j] = (d >= 16);
    }

    const int rW = w * 16 + n15;                 // this wave's K/V LDS row
    const int mS = (n15 & 7) << 4;               // fragment-read swizzle mask
    const int b0 = (g * 16) ^ mS;                // frag bytes (lo 32 keys/dims)
    const int b1 = (64 + g * 16) ^ mS;           // frag bytes (hi 32)

    // ---------------- pass A: row sums ----------------
    float lsum[4] = {0.f, 0.f, 0.f, 0.f};
    for (int t = 0; t < T; ++t) {
        const int k0 = t * 64;
        const int m_lo = 2032 + k0 - l0;
        __syncthreads();                         // prior tile's LDS reads done
        // stage K: 512 x 16B chunks, dense
        for (int c = tid; c < 512; c += 256) {
            const int row = c >> 3, bi = (c & 7) * 16;
            const short8 v = *reinterpret_cast<const short8*>(
                khp + (bhS + k0 + row) * kDH + (c & 7) * 8);
            *reinterpret_cast<short8*>(smem + kKl + row * 128 + (bi ^ ((row & 7) << 4))) = v;
        }
        // stage E window: 640 chunks (80 rows), clamped
        for (int c = tid; c < 640; c += 256) {
            const int row = c >> 3, bi = (c & 7) * 16;
            const int er = min(m_lo + row, kS - 1);   // clamped rows feed masked elems only
            const short8 v = *reinterpret_cast<const short8*>(
                eb + (size_t)er * kDH + (c & 7) * 8);
            *reinterpret_cast<short8*>(smem + kEl + row * 128 + (bi ^ ((row & 7) << 4))) = v;
        }
        __syncthreads();                         // staged data visible

        // scores: wave w owns ki-quadrant w
        f32x4 s4 = {0.f, 0.f, 0.f, 0.f};
        s4 = mfma16(aq0, *reinterpret_cast<const short8*>(smem + kKl + rW * 128 + b0), s4);
        s4 = mfma16(aq1, *reinterpret_cast<const short8*>(smem + kKl + rW * 128 + b1), s4);
        f32x4 qe2[2];
        #pragma unroll
        for (int q2 = 0; q2 < 2; ++q2) {
            const int rE = w * 16 + q2 * 16 + n15;
            f32x4 acc = {0.f, 0.f, 0.f, 0.f};
            acc = mfma16(aq0, *reinterpret_cast<const short8*>(smem + kEl + rE * 128 + b0), acc);
            qe2[q2] = mfma16(aq1, *reinterpret_cast<const short8*>(smem + kEl + rE * 128 + b1), acc);
        }
        #pragma unroll
        for (int j = 0; j < 4; ++j) {
            const float sh0 = __shfl(qe2[0][j], srcl[j]);
            const float sh1 = __shfl(qe2[1][j], srcl[j]);
            const float rel = condj[j] ? sh1 : sh0;
            float v = (s4[j] + rel) * 0.125f;
            v = fminf(v, 60.f);
            const bool keep = (k0 + w * 16 + n15 <= l0 + g * 4 + j);
            lsum[j] += keep ? __expf(v) : 0.f;
        }
    }
    #pragma unroll
    for (int j = 0; j < 4; ++j) {
        float s = lsum[j];
        #pragma unroll
        for (int off = 1; off < 16; off <<= 1) s += __shfl_xor(s, off);
        if (n15 == 0) lsum_s[w * 16 + g * 4 + j] = s;
    }
    __syncthreads();                             // lsum exchange

    float linv[4];
    #pragma unroll
    for (int j = 0; j < 4; ++j) {
        const int r = g * 4 + j;
        linv[j] = 1.f / (lsum_s[r] + lsum_s[16 + r] + lsum_s[32 + r] + lsum_s[48 + r]);
    }

    // ---------------- pass B: emit + PV ----------------
    f32x4 o = {0.f, 0.f, 0.f, 0.f};              // wave-private dh-quadrant w
    const int srow = tid >> 4;                   // store row 0..15
    const int scol = (tid & 15) * 4;             // store col (f32)

    for (int t = 0; t < 32; ++t) {
        const int k0 = t * 64;
        if (t >= T) {                            // fully masked: 1 f32x4/thread
            const f32x4 z = {0.f, 0.f, 0.f, 0.f};
            __builtin_nontemporal_store(
                z, reinterpret_cast<f32x4*>(attn + (bhS + l0 + srow) * kS + k0 + scol));
            continue;
        }
        const int m_lo = 2032 + k0 - l0;
        __syncthreads();                         // prior tile's LDS reads done
        for (int c = tid; c < 512; c += 256) {   // stage K
            const int row = c >> 3, bi = (c & 7) * 16;
            const short8 v = *reinterpret_cast<const short8*>(
                khp + (bhS + k0 + row) * kDH + (c & 7) * 8);
            *reinterpret_cast<short8*>(smem + kKl + row * 128 + (bi ^ ((row & 7) << 4))) = v;
        }
        for (int c = tid; c < 512; c += 256) {   // stage V^T
            const int row = c >> 3, bi = (c & 7) * 16;
            const short8 v = *reinterpret_cast<const short8*>(
                vt + ((size_t)bh * kDH + row) * kS + k0 + (c & 7) * 8);
            *reinterpret_cast<short8*>(smem + kVl + row * 128 + (bi ^ ((row & 7) << 4))) = v;
        }
        for (int c = tid; c < 640; c += 256) {   // stage E window
            const int row = c >> 3, bi = (c & 7) * 16;
            const int er = min(m_lo + row, kS - 1);
            const short8 v = *reinterpret_cast<const short8*>(
                eb + (size_t)er * kDH + (c & 7) * 8);
            *reinterpret_cast<short8*>(smem + kEl + row * 128 + (bi ^ ((row & 7) << 4))) = v;
        }
        __syncthreads();                         // staged data visible

        f32x4 s4 = {0.f, 0.f, 0.f, 0.f};
        s4 = mfma16(aq0, *reinterpret_cast<const short8*>(smem + kKl + rW * 128 + b0), s4);
        s4 = mfma16(aq1, *reinterpret_cast<const short8*>(smem + kKl + rW * 128 + b1), s4);
        f32x4 qe2[2];
        #pragma unroll
        for (int q2 = 0; q2 < 2; ++q2) {
            const int rE = w * 16 + q2 * 16 + n15;
            f32x4 acc = {0.f, 0.f, 0.f, 0.f};
            acc = mfma16(aq0, *reinterpret_cast<const short8*>(smem + kEl + rE * 128 + b0), acc);
            qe2[q2] = mfma16(aq1, *reinterpret_cast<const short8*>(smem + kEl + rE * 128 + b1), acc);
        }
        #pragma unroll
        for (int j = 0; j < 4; ++j) {
            const float sh0 = __shfl(qe2[0][j], srcl[j]);
            const float sh1 = __shfl(qe2[1][j], srcl[j]);
            const float rel = condj[j] ? sh1 : sh0;
            float v = (s4[j] + rel) * 0.125f;
            v = fminf(v, 60.f);
            const bool keep = (k0 + w * 16 + n15 <= l0 + g * 4 + j);
            const float pe = keep ? __expf(v) * linv[j] : 0.f;
            Pf[(g * 4 + j) * 68 + w * 16 + n15] = pe;
        }
        __syncthreads();                         // P visible

        // attn store: 1 f32x4 per thread, 256B-contiguous row segments
        const f32x4 pv4 = *reinterpret_cast<const f32x4*>(Pf + srow * 68 + scol);
        __builtin_nontemporal_store(
            pv4, reinterpret_cast<f32x4*>(attn + (bhS + l0 + srow) * kS + k0 + scol));

        // PV: wave w owns dh-quadrant w; A-frags from P, B-frags from V LDS
        const f32x4 plo0 = *reinterpret_cast<const f32x4*>(Pf + n15 * 68 + g * 8);
        const f32x4 phi0 = *reinterpret_cast<const f32x4*>(Pf + n15 * 68 + g * 8 + 4);
        const f32x4 plo1 = *reinterpret_cast<const f32x4*>(Pf + n15 * 68 + 32 + g * 8);
        const f32x4 phi1 = *reinterpret_cast<const f32x4*>(Pf + n15 * 68 + 32 + g * 8 + 4);
        short8 pa0, pa1;
        #pragma unroll
        for (int i = 0; i < 4; ++i) {
            pa0[i] = bfbits(plo0[i]); pa0[4 + i] = bfbits(phi0[i]);
            pa1[i] = bfbits(plo1[i]); pa1[4 + i] = bfbits(phi1[i]);
        }
        o = mfma16(pa0, *reinterpret_cast<const short8*>(smem + kVl + rW * 128 + b0), o);
        o = mfma16(pa1, *reinterpret_cast<const short8*>(smem + kVl + rW * 128 + b1), o);
        // next iteration's leading __syncthreads() protects P/K/V/E reuse
    }

    // epilogue: wave-private O -> ohb (B,S,D) bf16
    const int b = bh >> 3, h = bh & 7;
    #pragma unroll
    for (int j = 0; j < 4; ++j)
        ohb[((size_t)b * kS + l0 + g * 4 + j) * kD + h * kDH + w * 16 + n15] =
            (ushort)bfbits(o[j]);
}

// ---------------------------------------------------------------------------
extern "C" void kernel_launch(void* const* d_in, const int* in_sizes, int n_in,
                              void* d_out, int out_size, void* d_ws, size_t ws_size,
                              hipStream_t stream)
{
    const float* q_in = (const float*)d_in[0];
    const float* k_in = (const float*)d_in[1];
    const float* v_in = (const float*)d_in[2];
    const float* Wq = (const float*)d_in[4];
    const float* bq = (const float*)d_in[5];
    const float* Wk = (const float*)d_in[6];
    const float* bk = (const float*)d_in[7];
    const float* Wv = (const float*)d_in[8];
    const float* bv = (const float*)d_in[9];
    const float* Wo = (const float*)d_in[10];
    const float* bo = (const float*)d_in[11];
    const float* E  = (const float*)d_in[12];

    float* out  = (float*)d_out;                          // (B,S,D)
    float* attn = (float*)d_out + (size_t)kB * kS * kD;   // (B,H,S,S)

    // workspace: all bf16 (~31.7 MB)
    ushort* qh  = (ushort*)d_ws;          // (B,H,S,DH)
    ushort* kh  = qh  + 2097152;          // (B,H,S,DH)
    ushort* vt  = kh  + 2097152;          // (B,H,DH,S)
    ushort* ohb = vt  + 2097152;          // (B,S,D)
    ushort* qb  = ohb + 2097152;          // (B,S,D) inputs in bf16
    ushort* kb  = qb  + 2097152;
    ushort* vb  = kb  + 2097152;
    ushort* eb  = vb  + 2097152;          // (2048,64)
    ushort* Wqt = eb  + 131072;           // col-major 512x512
    ushort* Wkt = Wqt + 262144;
    ushort* Wvt = Wkt + 262144;
    ushort* Wot = Wvt + 262144;

    convw_kernel<<<dim3(8, 8, 5), 256, 0, stream>>>(Wq, Wk, Wv, Wo, E,
                                                    Wqt, Wkt, Wvt, Wot, eb);
    cvta_kernel<<<dim3(1024, 1, 3), 256, 0, stream>>>(q_in, k_in, v_in, qb, kb, vb);
    gemm_qkv_kernel<<<dim3(64, 16, 3), 256, 0, stream>>>(qb, kb, vb,
                                                         Wqt, Wkt, Wvt,
                                                         bq, bk, bv, qh, kh, vt);
    attn_fused_kernel<<<dim3(16, 128), 256, 0, stream>>>(qh, kh, vt, eb, attn, ohb);
    gemm_o_kernel<<<dim3(64, 16), 256, 0, stream>>>(ohb, Wot, bo, out);
}

// Round 15
// 160.266 us; speedup vs baseline: 2.1216x; 1.3894x over previous
//
#include <hip/hip_runtime.h>
#include <hip/hip_bf16.h>

// RelativeGlobalAttention: B=2, S=2048, D=512, H=8, DH=64, MAX_SEQ=2048
// out0 = attention output (B,S,D); out1 = attn probs (B,H,S,S); concatenated.
//
// Identity: srel[l,k] = q[l].E[2047-l+k] for k<=l, else 0.
// logits = (QK^T + srel)/8; causal mask => masked probs exactly 0.
// No-max softmax: exp(v)/sum(exp(v)) == reference softmax up to fp32 rounding.
//
// R15 = R13 attn (verified win: dense staging kills address divergence) +
// the SAME fix applied to the GEMMs: LDS-staged tiles (BM=64,BN=32,BK=64),
// dense 32B/thread global loads, fp32->bf16 conversion during staging
// (cvta kernel deleted), MFMA fragments from XOR-swizzled LDS.

namespace {
constexpr int kS  = 2048;
constexpr int kD  = 512;
constexpr int kH  = 8;
constexpr int kDH = 64;
constexpr int kB  = 2;

typedef __attribute__((ext_vector_type(8))) short short8;   // 8 x bf16
typedef __attribute__((ext_vector_type(4))) float f32x4;

// attn LDS layout (bytes)
constexpr int kKl = 0;        // K tile: 64 rows x 128B, swizzled
constexpr int kVl = 8192;     // V^T tile: 64 dh-rows x 128B, swizzled
constexpr int kEl = 16384;    // E window: 80 rows x 128B, swizzled
constexpr int kPf = 26624;    // P: 16 x 68 f32
constexpr int kLs = 30976;    // lsum_s: 64 f32
}

__device__ __forceinline__ f32x4 mfma16(short8 a, short8 b, f32x4 c) {
    return __builtin_amdgcn_mfma_f32_16x16x32_bf16(a, b, c, 0, 0, 0);
}

__device__ __forceinline__ short bfbits(float f) {
    __hip_bfloat16 h = __float2bfloat16(f);
    return *reinterpret_cast<short*>(&h);
}

// ---------------------------------------------------------------------------
// conv: W (512x512 fp32 row-major) -> Wt (bf16 col-major [c][k]) x4; E -> bf16
// ---------------------------------------------------------------------------
__global__ __launch_bounds__(256)
void convw_kernel(const float* __restrict__ Wq, const float* __restrict__ Wk,
                  const float* __restrict__ Wv, const float* __restrict__ Wo,
                  const float* __restrict__ E,
                  ushort* __restrict__ Wqt, ushort* __restrict__ Wkt,
                  ushort* __restrict__ Wvt, ushort* __restrict__ Wot,
                  ushort* __restrict__ eb)
{
    const int z = blockIdx.z;
    const int tid = threadIdx.x;
    if (z == 4) {   // E: 2048x64 = 131072 elems
        const int idx = ((blockIdx.y * 8 + blockIdx.x) * 256 + tid) * 8;
        const float4 x = *reinterpret_cast<const float4*>(E + idx);
        const float4 y = *reinterpret_cast<const float4*>(E + idx + 4);
        short8 r;
        r[0] = bfbits(x.x); r[1] = bfbits(x.y); r[2] = bfbits(x.z); r[3] = bfbits(x.w);
        r[4] = bfbits(y.x); r[5] = bfbits(y.y); r[6] = bfbits(y.z); r[7] = bfbits(y.w);
        *reinterpret_cast<short8*>(eb + idx) = r;
        return;
    }
    const float* W = (z == 0) ? Wq : (z == 1) ? Wk : (z == 2) ? Wv : Wo;
    ushort* Wt = (z == 0) ? Wqt : (z == 1) ? Wkt : (z == 2) ? Wvt : Wot;

    __shared__ float Ws[64][65];
    const int k0 = blockIdx.x * 64;
    const int c0 = blockIdx.y * 64;
    const int cc = tid & 63;
    const int rq = tid >> 6;
    #pragma unroll
    for (int ii = 0; ii < 16; ++ii) {
        const int r = ii * 4 + rq;
        Ws[r][cc] = W[(size_t)(k0 + r) * kD + c0 + cc];
    }
    __syncthreads();
    #pragma unroll
    for (int ii = 0; ii < 16; ++ii) {
        const int r = ii * 4 + rq;
        Wt[(size_t)(c0 + r) * kD + k0 + cc] = (ushort)bfbits(Ws[cc][r]);
    }
}

// ---------------------------------------------------------------------------
// LDS-staged MFMA GEMM: C(4096x512) = A(4096x512) @ W + bias.
// W as bf16 col-major Wt[c][k]. BM=64, BN=32, BK=64; 256 thr = 4 waves;
// wave w owns rows w*16..+16 x all 32 cols. Dense staging: A fp32 (AF32) or
// bf16, 32B contiguous per thread; swizzled LDS; fragments from LDS.
// MODE: 0 = fp32 (B,S,D); 1 = bf16 (B,H,S,DH); 2 = bf16 (B,H,DH,S)
// ---------------------------------------------------------------------------
template<int MODE, bool AF32>
__device__ __forceinline__
void gemm_lds_core(char* lds, const void* __restrict__ Av,
                   const ushort* __restrict__ Wt,
                   const float* __restrict__ bias, void* __restrict__ out)
{
    char* As = lds;           // 64 rows x 128B, swizzled
    char* Ws = lds + 8192;    // 32 c-rows x 128B, swizzled

    const int tid  = threadIdx.x;
    const int w    = tid >> 6;
    const int lane = tid & 63;
    const int g    = lane >> 4;
    const int n15  = lane & 15;
    const int r0   = blockIdx.x * 64;
    const int c0   = blockIdx.y * 32;

    f32x4 acc0 = {0.f, 0.f, 0.f, 0.f};
    f32x4 acc1 = {0.f, 0.f, 0.f, 0.f};

    const int rA  = w * 16 + n15;                // frag row (A)
    const int swA = (n15 & 7) << 4;              // (rA&7)<<4 == (n15&7)<<4
    const int swB = (n15 & 7) << 4;              // (crow&7)<<4 for n15 and 16+n15

    for (int kb = 0; kb < 8; ++kb) {
        const int k0 = kb * 64;
        __syncthreads();                         // prev iter's frag reads done
        // stage A: 512 chunks (row=c>>3, i=c&7), 2 per thread, 32B contiguous
        #pragma unroll
        for (int hh = 0; hh < 2; ++hh) {
            const int c = tid + hh * 256;
            const int row = c >> 3, i = c & 7;
            short8 v;
            if (AF32) {
                const float* src = (const float*)Av + (size_t)(r0 + row) * kD + k0 + i * 8;
                const float4 x = *reinterpret_cast<const float4*>(src);
                const float4 y = *reinterpret_cast<const float4*>(src + 4);
                v[0] = bfbits(x.x); v[1] = bfbits(x.y); v[2] = bfbits(x.z); v[3] = bfbits(x.w);
                v[4] = bfbits(y.x); v[5] = bfbits(y.y); v[6] = bfbits(y.z); v[7] = bfbits(y.w);
            } else {
                v = *reinterpret_cast<const short8*>(
                    (const ushort*)Av + (size_t)(r0 + row) * kD + k0 + i * 8);
            }
            *reinterpret_cast<short8*>(As + row * 128 + ((i * 16) ^ ((row & 7) << 4))) = v;
        }
        // stage W: 256 chunks (crow=tid>>3, i=tid&7), 1 per thread
        {
            const int crow = tid >> 3, i = tid & 7;
            const short8 v = *reinterpret_cast<const short8*>(
                Wt + (size_t)(c0 + crow) * kD + k0 + i * 8);
            *reinterpret_cast<short8*>(Ws + crow * 128 + ((i * 16) ^ ((crow & 7) << 4))) = v;
        }
        __syncthreads();                         // staged data visible

        #pragma unroll
        for (int ks = 0; ks < 2; ++ks) {
            const int bo = ks * 64 + g * 16;
            const short8 a  = *reinterpret_cast<const short8*>(As + rA * 128 + (bo ^ swA));
            const short8 b0 = *reinterpret_cast<const short8*>(Ws + n15 * 128 + (bo ^ swB));
            const short8 b1 = *reinterpret_cast<const short8*>(Ws + (16 + n15) * 128 + (bo ^ swB));
            acc0 = mfma16(a, b0, acc0);
            acc1 = mfma16(a, b1, acc1);
        }
    }

    #pragma unroll
    for (int cg = 0; cg < 2; ++cg) {
        const f32x4 acc = cg ? acc1 : acc0;
        const int c = c0 + cg * 16 + n15;
        const float bb = bias[c];
        const int h = c >> 6, d = c & (kDH - 1);
        #pragma unroll
        for (int j = 0; j < 4; ++j) {
            const int r = r0 + w * 16 + g * 4 + j;
            const float val = acc[j] + bb;
            const int b = r >> 11, s2 = r & (kS - 1);
            if (MODE == 0) {
                ((float*)out)[(size_t)r * kD + c] = val;
            } else if (MODE == 1) {
                ((ushort*)out)[((size_t)(b * kH + h) * kS + s2) * kDH + d] = (ushort)bfbits(val);
            } else {
                ((ushort*)out)[((size_t)(b * kH + h) * kDH + d) * kS + s2] = (ushort)bfbits(val);
            }
        }
    }
}

__global__ __launch_bounds__(256)
void gemm_qkv_kernel(const float* __restrict__ q_in, const float* __restrict__ k_in,
                     const float* __restrict__ v_in,
                     const ushort* __restrict__ Wqt, const ushort* __restrict__ Wkt,
                     const ushort* __restrict__ Wvt,
                     const float* __restrict__ bq, const float* __restrict__ bk,
                     const float* __restrict__ bv,
                     ushort* __restrict__ qh, ushort* __restrict__ kh,
                     ushort* __restrict__ vt)
{
    __shared__ __align__(16) char lds[12288];
    const int z = blockIdx.z;
    const float*  A    = (z == 0) ? q_in : (z == 1) ? k_in : v_in;
    const ushort* Wt   = (z == 0) ? Wqt  : (z == 1) ? Wkt  : Wvt;
    const float*  bias = (z == 0) ? bq   : (z == 1) ? bk   : bv;
    void*         out  = (z == 0) ? (void*)qh : (z == 1) ? (void*)kh : (void*)vt;
    if (z == 2) gemm_lds_core<2, true>(lds, A, Wt, bias, out);
    else        gemm_lds_core<1, true>(lds, A, Wt, bias, out);
}

__global__ __launch_bounds__(256)
void gemm_o_kernel(const ushort* __restrict__ ohb, const ushort* __restrict__ Wot,
                   const float* __restrict__ bo, float* __restrict__ out)
{
    __shared__ __align__(16) char lds[12288];
    gemm_lds_core<0, false>(lds, ohb, Wot, bo, out);
}

// ---------------------------------------------------------------------------
// Fused attention, LDS-staged (R13, unchanged). Block = (bh, strip), 4 waves.
// ---------------------------------------------------------------------------
__global__ __launch_bounds__(256, 4)
void attn_fused_kernel(const ushort* __restrict__ qh, const ushort* __restrict__ khp,
                       const ushort* __restrict__ vt, const ushort* __restrict__ eb,
                       float* __restrict__ attn, ushort* __restrict__ ohb)
{
    __shared__ __align__(16) char smem[31232];
    float* Pf     = (float*)(smem + kPf);
    float* lsum_s = (float*)(smem + kLs);

    const int bh    = blockIdx.x;
    const int strip = 127 - (int)blockIdx.y;     // big-work-first
    const int l0    = strip * 16;
    const int tid   = threadIdx.x;
    const int w     = tid >> 6;
    const int lane  = tid & 63;
    const int g     = lane >> 4;
    const int n15   = lane & 15;
    const size_t bhS = (size_t)bh * kS;

    const int T = ((l0 + 15) >> 6) + 1;          // causal 64-wide tiles

    const ushort* qrow = qh + (bhS + l0 + n15) * kDH;
    const short8 aq0 = *reinterpret_cast<const short8*>(qrow + g * 8);
    const short8 aq1 = *reinterpret_cast<const short8*>(qrow + 32 + g * 8);

    int  srcl[4];
    bool condj[4];
    #pragma unroll
    for (int j = 0; j < 4; ++j) {
        const int d = n15 + 15 - (g * 4 + j);
        srcl[j]  = (lane & 48) | (d & 15);
        condj[j] = (d >= 16);
    }

    const int rW = w * 16 + n15;                 // this wave's K/V LDS row
    const int mS = (n15 & 7) << 4;
    const int b0 = (g * 16) ^ mS;
    const int b1 = (64 + g * 16) ^ mS;

    // ---------------- pass A: row sums ----------------
    float lsum[4] = {0.f, 0.f, 0.f, 0.f};
    for (int t = 0; t < T; ++t) {
        const int k0 = t * 64;
        const int m_lo = 2032 + k0 - l0;
        __syncthreads();
        for (int c = tid; c < 512; c += 256) {
            const int row = c >> 3, bi = (c & 7) * 16;
            const short8 v = *reinterpret_cast<const short8*>(
                khp + (bhS + k0 + row) * kDH + (c & 7) * 8);
            *reinterpret_cast<short8*>(smem + kKl + row * 128 + (bi ^ ((row & 7) << 4))) = v;
        }
        for (int c = tid; c < 640; c += 256) {
            const int row = c >> 3, bi = (c & 7) * 16;
            const int er = min(m_lo + row, kS - 1);
            const short8 v = *reinterpret_cast<const short8*>(
                eb + (size_t)er * kDH + (c & 7) * 8);
            *reinterpret_cast<short8*>(smem + kEl + row * 128 + (bi ^ ((row & 7) << 4))) = v;
        }
        __syncthreads();

        f32x4 s4 = {0.f, 0.f, 0.f, 0.f};
        s4 = mfma16(aq0, *reinterpret_cast<const short8*>(smem + kKl + rW * 128 + b0), s4);
        s4 = mfma16(aq1, *reinterpret_cast<const short8*>(smem + kKl + rW * 128 + b1), s4);
        f32x4 qe2[2];
        #pragma unroll
        for (int q2 = 0; q2 < 2; ++q2) {
            const int rE = w * 16 + q2 * 16 + n15;
            f32x4 acc = {0.f, 0.f, 0.f, 0.f};
            acc = mfma16(aq0, *reinterpret_cast<const short8*>(smem + kEl + rE * 128 + b0), acc);
            qe2[q2] = mfma16(aq1, *reinterpret_cast<const short8*>(smem + kEl + rE * 128 + b1), acc);
        }
        #pragma unroll
        for (int j = 0; j < 4; ++j) {
            const float sh0 = __shfl(qe2[0][j], srcl[j]);
            const float sh1 = __shfl(qe2[1][j], srcl[j]);
            const float rel = condj[j] ? sh1 : sh0;
            float v = (s4[j] + rel) * 0.125f;
            v = fminf(v, 60.f);
            const bool keep = (k0 + w * 16 + n15 <= l0 + g * 4 + j);
            lsum[j] += keep ? __expf(v) : 0.f;
        }
    }
    #pragma unroll
    for (int j = 0; j < 4; ++j) {
        float s = lsum[j];
        #pragma unroll
        for (int off = 1; off < 16; off <<= 1) s += __shfl_xor(s, off);
        if (n15 == 0) lsum_s[w * 16 + g * 4 + j] = s;
    }
    __syncthreads();

    float linv[4];
    #pragma unroll
    for (int j = 0; j < 4; ++j) {
        const int r = g * 4 + j;
        linv[j] = 1.f / (lsum_s[r] + lsum_s[16 + r] + lsum_s[32 + r] + lsum_s[48 + r]);
    }

    // ---------------- pass B: emit + PV ----------------
    f32x4 o = {0.f, 0.f, 0.f, 0.f};
    const int srow = tid >> 4;
    const int scol = (tid & 15) * 4;

    for (int t = 0; t < 32; ++t) {
        const int k0 = t * 64;
        if (t >= T) {
            const f32x4 z = {0.f, 0.f, 0.f, 0.f};
            __builtin_nontemporal_store(
                z, reinterpret_cast<f32x4*>(attn + (bhS + l0 + srow) * kS + k0 + scol));
            continue;
        }
        const int m_lo = 2032 + k0 - l0;
        __syncthreads();
        for (int c = tid; c < 512; c += 256) {
            const int row = c >> 3, bi = (c & 7) * 16;
            const short8 v = *reinterpret_cast<const short8*>(
                khp + (bhS + k0 + row) * kDH + (c & 7) * 8);
            *reinterpret_cast<short8*>(smem + kKl + row * 128 + (bi ^ ((row & 7) << 4))) = v;
        }
        for (int c = tid; c < 512; c += 256) {
            const int row = c >> 3, bi = (c & 7) * 16;
            const short8 v = *reinterpret_cast<const short8*>(
                vt + ((size_t)bh * kDH + row) * kS + k0 + (c & 7) * 8);
            *reinterpret_cast<short8*>(smem + kVl + row * 128 + (bi ^ ((row & 7) << 4))) = v;
        }
        for (int c = tid; c < 640; c += 256) {
            const int row = c >> 3, bi = (c & 7) * 16;
            const int er = min(m_lo + row, kS - 1);
            const short8 v = *reinterpret_cast<const short8*>(
                eb + (size_t)er * kDH + (c & 7) * 8);
            *reinterpret_cast<short8*>(smem + kEl + row * 128 + (bi ^ ((row & 7) << 4))) = v;
        }
        __syncthreads();

        f32x4 s4 = {0.f, 0.f, 0.f, 0.f};
        s4 = mfma16(aq0, *reinterpret_cast<const short8*>(smem + kKl + rW * 128 + b0), s4);
        s4 = mfma16(aq1, *reinterpret_cast<const short8*>(smem + kKl + rW * 128 + b1), s4);
        f32x4 qe2[2];
        #pragma unroll
        for (int q2 = 0; q2 < 2; ++q2) {
            const int rE = w * 16 + q2 * 16 + n15;
            f32x4 acc = {0.f, 0.f, 0.f, 0.f};
            acc = mfma16(aq0, *reinterpret_cast<const short8*>(smem + kEl + rE * 128 + b0), acc);
            qe2[q2] = mfma16(aq1, *reinterpret_cast<const short8*>(smem + kEl + rE * 128 + b1), acc);
        }
        #pragma unroll
        for (int j = 0; j < 4; ++j) {
            const float sh0 = __shfl(qe2[0][j], srcl[j]);
            const float sh1 = __shfl(qe2[1][j], srcl[j]);
            const float rel = condj[j] ? sh1 : sh0;
            float v = (s4[j] + rel) * 0.125f;
            v = fminf(v, 60.f);
            const bool keep = (k0 + w * 16 + n15 <= l0 + g * 4 + j);
            const float pe = keep ? __expf(v) * linv[j] : 0.f;
            Pf[(g * 4 + j) * 68 + w * 16 + n15] = pe;
        }
        __syncthreads();

        const f32x4 pv4 = *reinterpret_cast<const f32x4*>(Pf + srow * 68 + scol);
        __builtin_nontemporal_store(
            pv4, reinterpret_cast<f32x4*>(attn + (bhS + l0 + srow) * kS + k0 + scol));

        const f32x4 plo0 = *reinterpret_cast<const f32x4*>(Pf + n15 * 68 + g * 8);
        const f32x4 phi0 = *reinterpret_cast<const f32x4*>(Pf + n15 * 68 + g * 8 + 4);
        const f32x4 plo1 = *reinterpret_cast<const f32x4*>(Pf + n15 * 68 + 32 + g * 8);
        const f32x4 phi1 = *reinterpret_cast<const f32x4*>(Pf + n15 * 68 + 32 + g * 8 + 4);
        short8 pa0, pa1;
        #pragma unroll
        for (int i = 0; i < 4; ++i) {
            pa0[i] = bfbits(plo0[i]); pa0[4 + i] = bfbits(phi0[i]);
            pa1[i] = bfbits(plo1[i]); pa1[4 + i] = bfbits(phi1[i]);
        }
        o = mfma16(pa0, *reinterpret_cast<const short8*>(smem + kVl + rW * 128 + b0), o);
        o = mfma16(pa1, *reinterpret_cast<const short8*>(smem + kVl + rW * 128 + b1), o);
    }

    const int b = bh >> 3, h = bh & 7;
    #pragma unroll
    for (int j = 0; j < 4; ++j)
        ohb[((size_t)b * kS + l0 + g * 4 + j) * kD + h * kDH + w * 16 + n15] =
            (ushort)bfbits(o[j]);
}

// ---------------------------------------------------------------------------
extern "C" void kernel_launch(void* const* d_in, const int* in_sizes, int n_in,
                              void* d_out, int out_size, void* d_ws, size_t ws_size,
                              hipStream_t stream)
{
    const float* q_in = (const float*)d_in[0];
    const float* k_in = (const float*)d_in[1];
    const float* v_in = (const float*)d_in[2];
    const float* Wq = (const float*)d_in[4];
    const float* bq = (const float*)d_in[5];
    const float* Wk = (const float*)d_in[6];
    const float* bk = (const float*)d_in[7];
    const float* Wv = (const float*)d_in[8];
    const float* bv = (const float*)d_in[9];
    const float* Wo = (const float*)d_in[10];
    const float* bo = (const float*)d_in[11];
    const float* E  = (const float*)d_in[12];

    float* out  = (float*)d_out;                          // (B,S,D)
    float* attn = (float*)d_out + (size_t)kB * kS * kD;   // (B,H,S,S)

    // workspace: all bf16 (~19 MB)
    ushort* qh  = (ushort*)d_ws;          // (B,H,S,DH)
    ushort* kh  = qh  + 2097152;          // (B,H,S,DH)
    ushort* vt  = kh  + 2097152;          // (B,H,DH,S)
    ushort* ohb = vt  + 2097152;          // (B,S,D)
    ushort* eb  = ohb + 2097152;          // (2048,64)
    ushort* Wqt = eb  + 131072;           // col-major 512x512
    ushort* Wkt = Wqt + 262144;
    ushort* Wvt = Wkt + 262144;
    ushort* Wot = Wvt + 262144;

    convw_kernel<<<dim3(8, 8, 5), 256, 0, stream>>>(Wq, Wk, Wv, Wo, E,
                                                    Wqt, Wkt, Wvt, Wot, eb);
    gemm_qkv_kernel<<<dim3(64, 16, 3), 256, 0, stream>>>(q_in, k_in, v_in,
                                                         Wqt, Wkt, Wvt,
                                                         bq, bk, bv, qh, kh, vt);
    attn_fused_kernel<<<dim3(16, 128), 256, 0, stream>>>(qh, kh, vt, eb, attn, ohb);
    gemm_o_kernel<<<dim3(64, 16), 256, 0, stream>>>(ohb, Wot, bo, out);
}

// Round 16
// 137.563 us; speedup vs baseline: 2.4717x; 1.1650x over previous
//
#include <hip/hip_runtime.h>
#include <hip/hip_bf16.h>

// RelativeGlobalAttention: B=2, S=2048, D=512, H=8, DH=64, MAX_SEQ=2048
// out0 = attention output (B,S,D); out1 = attn probs (B,H,S,S); concatenated.
//
// Identity: srel[l,k] = q[l].E[2047-l+k] for k<=l, else 0.
// logits = (QK^T + srel)/8; causal mask => masked probs exactly 0.
// No-max softmax: exp(v)/sum(exp(v)) == reference softmax up to fp32 rounding.
//
// R16 = R15 + P-store: pass A stores unnormalized exp (bf16) to a packed
// triangular ws (same block re-reads -> L2-resident); pass B drops K/E
// staging and score recompute entirely (emit = bf16P * linv; PV on bf16 P,
// O scaled by linv at epilogue). LDS 31->18.3KB, launch_bounds(256,6) = 24
// waves/CU. Host falls back to the R15 kernel if ws_size < ~88MB.

namespace {
constexpr int kS  = 2048;
constexpr int kD  = 512;
constexpr int kH  = 8;
constexpr int kDH = 64;
constexpr int kB  = 2;

typedef __attribute__((ext_vector_type(8))) short short8;   // 8 x bf16
typedef __attribute__((ext_vector_type(4))) short short4v;  // 4 x bf16 (8B)
typedef __attribute__((ext_vector_type(4))) float f32x4;

// R15 fallback attn LDS layout (bytes)
constexpr int kKl = 0;        // K tile: 64 rows x 128B, swizzled
constexpr int kVl = 8192;     // V^T tile: 64 dh-rows x 128B, swizzled
constexpr int kEl = 16384;    // E window: 80 rows x 128B, swizzled
constexpr int kPf = 26624;    // P: 16 x 68 f32
constexpr int kLs = 30976;    // lsum_s: 64 f32

// R16 P-store attn LDS layout (bytes). Pass A uses K@0 + E@8192;
// pass B overlays V@0 + P@8192 (disjoint in time).
constexpr int pKl = 0;        // K tile (pass A)  / V tile (pass B)
constexpr int pPl = 8192;     // P tile bf16 16x128B (pass B), inside E region
constexpr int pEl = 8192;     // E window 80x128B (pass A)
constexpr int pLs = 18432;    // lsum_s: 64 f32
constexpr int pLi = 18688;    // linv_s: 16 f32
constexpr int pSz = 18752;

constexpr size_t kPwsElems = (size_t)16 * 2112 * 1024;  // packed P, bf16
}

__device__ __forceinline__ f32x4 mfma16(short8 a, short8 b, f32x4 c) {
    return __builtin_amdgcn_mfma_f32_16x16x32_bf16(a, b, c, 0, 0, 0);
}

__device__ __forceinline__ short bfbits(float f) {
    __hip_bfloat16 h = __float2bfloat16(f);
    return *reinterpret_cast<short*>(&h);
}

__device__ __forceinline__ float bf2f(short b) {
    const unsigned u = (unsigned)(unsigned short)b << 16;
    return __uint_as_float(u);
}

// ---------------------------------------------------------------------------
// conv: W (512x512 fp32 row-major) -> Wt (bf16 col-major [c][k]) x4; E -> bf16
// ---------------------------------------------------------------------------
__global__ __launch_bounds__(256)
void convw_kernel(const float* __restrict__ Wq, const float* __restrict__ Wk,
                  const float* __restrict__ Wv, const float* __restrict__ Wo,
                  const float* __restrict__ E,
                  ushort* __restrict__ Wqt, ushort* __restrict__ Wkt,
                  ushort* __restrict__ Wvt, ushort* __restrict__ Wot,
                  ushort* __restrict__ eb)
{
    const int z = blockIdx.z;
    const int tid = threadIdx.x;
    if (z == 4) {   // E: 2048x64 = 131072 elems
        const int idx = ((blockIdx.y * 8 + blockIdx.x) * 256 + tid) * 8;
        const float4 x = *reinterpret_cast<const float4*>(E + idx);
        const float4 y = *reinterpret_cast<const float4*>(E + idx + 4);
        short8 r;
        r[0] = bfbits(x.x); r[1] = bfbits(x.y); r[2] = bfbits(x.z); r[3] = bfbits(x.w);
        r[4] = bfbits(y.x); r[5] = bfbits(y.y); r[6] = bfbits(y.z); r[7] = bfbits(y.w);
        *reinterpret_cast<short8*>(eb + idx) = r;
        return;
    }
    const float* W = (z == 0) ? Wq : (z == 1) ? Wk : (z == 2) ? Wv : Wo;
    ushort* Wt = (z == 0) ? Wqt : (z == 1) ? Wkt : (z == 2) ? Wvt : Wot;

    __shared__ float Ws[64][65];
    const int k0 = blockIdx.x * 64;
    const int c0 = blockIdx.y * 64;
    const int cc = tid & 63;
    const int rq = tid >> 6;
    #pragma unroll
    for (int ii = 0; ii < 16; ++ii) {
        const int r = ii * 4 + rq;
        Ws[r][cc] = W[(size_t)(k0 + r) * kD + c0 + cc];
    }
    __syncthreads();
    #pragma unroll
    for (int ii = 0; ii < 16; ++ii) {
        const int r = ii * 4 + rq;
        Wt[(size_t)(c0 + r) * kD + k0 + cc] = (ushort)bfbits(Ws[cc][r]);
    }
}

// ---------------------------------------------------------------------------
// LDS-staged MFMA GEMM (R15, unchanged)
// ---------------------------------------------------------------------------
template<int MODE, bool AF32>
__device__ __forceinline__
void gemm_lds_core(char* lds, const void* __restrict__ Av,
                   const ushort* __restrict__ Wt,
                   const float* __restrict__ bias, void* __restrict__ out)
{
    char* As = lds;
    char* Ws = lds + 8192;

    const int tid  = threadIdx.x;
    const int w    = tid >> 6;
    const int lane = tid & 63;
    const int g    = lane >> 4;
    const int n15  = lane & 15;
    const int r0   = blockIdx.x * 64;
    const int c0   = blockIdx.y * 32;

    f32x4 acc0 = {0.f, 0.f, 0.f, 0.f};
    f32x4 acc1 = {0.f, 0.f, 0.f, 0.f};

    const int rA  = w * 16 + n15;
    const int swA = (n15 & 7) << 4;
    const int swB = (n15 & 7) << 4;

    for (int kb = 0; kb < 8; ++kb) {
        const int k0 = kb * 64;
        __syncthreads();
        #pragma unroll
        for (int hh = 0; hh < 2; ++hh) {
            const int c = tid + hh * 256;
            const int row = c >> 3, i = c & 7;
            short8 v;
            if (AF32) {
                const float* src = (const float*)Av + (size_t)(r0 + row) * kD + k0 + i * 8;
                const float4 x = *reinterpret_cast<const float4*>(src);
                const float4 y = *reinterpret_cast<const float4*>(src + 4);
                v[0] = bfbits(x.x); v[1] = bfbits(x.y); v[2] = bfbits(x.z); v[3] = bfbits(x.w);
                v[4] = bfbits(y.x); v[5] = bfbits(y.y); v[6] = bfbits(y.z); v[7] = bfbits(y.w);
            } else {
                v = *reinterpret_cast<const short8*>(
                    (const ushort*)Av + (size_t)(r0 + row) * kD + k0 + i * 8);
            }
            *reinterpret_cast<short8*>(As + row * 128 + ((i * 16) ^ ((row & 7) << 4))) = v;
        }
        {
            const int crow = tid >> 3, i = tid & 7;
            const short8 v = *reinterpret_cast<const short8*>(
                Wt + (size_t)(c0 + crow) * kD + k0 + i * 8);
            *reinterpret_cast<short8*>(Ws + crow * 128 + ((i * 16) ^ ((crow & 7) << 4))) = v;
        }
        __syncthreads();

        #pragma unroll
        for (int ks = 0; ks < 2; ++ks) {
            const int bo = ks * 64 + g * 16;
            const short8 a  = *reinterpret_cast<const short8*>(As + rA * 128 + (bo ^ swA));
            const short8 b0 = *reinterpret_cast<const short8*>(Ws + n15 * 128 + (bo ^ swB));
            const short8 b1 = *reinterpret_cast<const short8*>(Ws + (16 + n15) * 128 + (bo ^ swB));
            acc0 = mfma16(a, b0, acc0);
            acc1 = mfma16(a, b1, acc1);
        }
    }

    #pragma unroll
    for (int cg = 0; cg < 2; ++cg) {
        const f32x4 acc = cg ? acc1 : acc0;
        const int c = c0 + cg * 16 + n15;
        const float bb = bias[c];
        const int h = c >> 6, d = c & (kDH - 1);
        #pragma unroll
        for (int j = 0; j < 4; ++j) {
            const int r = r0 + w * 16 + g * 4 + j;
            const float val = acc[j] + bb;
            const int b = r >> 11, s2 = r & (kS - 1);
            if (MODE == 0) {
                ((float*)out)[(size_t)r * kD + c] = val;
            } else if (MODE == 1) {
                ((ushort*)out)[((size_t)(b * kH + h) * kS + s2) * kDH + d] = (ushort)bfbits(val);
            } else {
                ((ushort*)out)[((size_t)(b * kH + h) * kDH + d) * kS + s2] = (ushort)bfbits(val);
            }
        }
    }
}

__global__ __launch_bounds__(256)
void gemm_qkv_kernel(const float* __restrict__ q_in, const float* __restrict__ k_in,
                     const float* __restrict__ v_in,
                     const ushort* __restrict__ Wqt, const ushort* __restrict__ Wkt,
                     const ushort* __restrict__ Wvt,
                     const float* __restrict__ bq, const float* __restrict__ bk,
                     const float* __restrict__ bv,
                     ushort* __restrict__ qh, ushort* __restrict__ kh,
                     ushort* __restrict__ vt)
{
    __shared__ __align__(16) char lds[12288];
    const int z = blockIdx.z;
    const float*  A    = (z == 0) ? q_in : (z == 1) ? k_in : v_in;
    const ushort* Wt   = (z == 0) ? Wqt  : (z == 1) ? Wkt  : Wvt;
    const float*  bias = (z == 0) ? bq   : (z == 1) ? bk   : bv;
    void*         out  = (z == 0) ? (void*)qh : (z == 1) ? (void*)kh : (void*)vt;
    if (z == 2) gemm_lds_core<2, true>(lds, A, Wt, bias, out);
    else        gemm_lds_core<1, true>(lds, A, Wt, bias, out);
}

__global__ __launch_bounds__(256)
void gemm_o_kernel(const ushort* __restrict__ ohb, const ushort* __restrict__ Wot,
                   const float* __restrict__ bo, float* __restrict__ out)
{
    __shared__ __align__(16) char lds[12288];
    gemm_lds_core<0, false>(lds, ohb, Wot, bo, out);
}

// ---------------------------------------------------------------------------
// R16 attention with P-store. Block = (bh, 16-row strip), 4 waves.
// Pass A: stage K/E, compute scores once, store bf16 exp to packed ws,
// accumulate lsum. Pass B: stage V + P tile (dense), emit attn = P*linv,
// PV on bf16 P, O scaled by linv at epilogue. grid (16,128) x 256.
// ---------------------------------------------------------------------------
__global__ __launch_bounds__(256, 6)
void attn_ps_kernel(const ushort* __restrict__ qh, const ushort* __restrict__ khp,
                    const ushort* __restrict__ vt, const ushort* __restrict__ eb,
                    float* __restrict__ attn, ushort* __restrict__ ohb,
                    ushort* __restrict__ Pws)
{
    __shared__ __align__(16) char smem[pSz];
    float* lsum_s = (float*)(smem + pLs);
    float* linv_s = (float*)(smem + pLi);

    const int bh    = blockIdx.x;
    const int strip = 127 - (int)blockIdx.y;     // big-work-first
    const int l0    = strip * 16;
    const int tid   = threadIdx.x;
    const int w     = tid >> 6;
    const int lane  = tid & 63;
    const int g     = lane >> 4;
    const int n15   = lane & 15;
    const size_t bhS = (size_t)bh * kS;

    const int T = (strip >> 2) + 1;              // causal 64-wide tiles

    // packed P base: sum_{s'<strip} T(s') = strip + 2a(a-1) + a*b
    const int pa_ = strip >> 2, pb_ = strip & 3;
    const int pbase = strip + 2 * pa_ * (pa_ - 1) + pa_ * pb_;
    ushort* Pstrip = Pws + ((size_t)bh * 2112 + pbase) * 1024;

    // Q fragments
    const ushort* qrow = qh + (bhS + l0 + n15) * kDH;
    const short8 aq0 = *reinterpret_cast<const short8*>(qrow + g * 8);
    const short8 aq1 = *reinterpret_cast<const short8*>(qrow + 32 + g * 8);

    int  srcl[4];
    bool condj[4];
    #pragma unroll
    for (int j = 0; j < 4; ++j) {
        const int d = n15 + 15 - (g * 4 + j);
        srcl[j]  = (lane & 48) | (d & 15);
        condj[j] = (d >= 16);
    }

    const int rW = w * 16 + n15;                 // K/V LDS row
    const int mS = (n15 & 7) << 4;
    const int b0 = (g * 16) ^ mS;
    const int b1 = (64 + g * 16) ^ mS;
    const int pcol = w * 16 + n15;               // this thread's P column

    // ---------------- pass A: scores once -> P store + lsum ----------------
    float lsum[4] = {0.f, 0.f, 0.f, 0.f};
    for (int t = 0; t < T; ++t) {
        const int k0 = t * 64;
        const int m_lo = 2032 + k0 - l0;
        __syncthreads();                         // prior tile's LDS reads done
        for (int c = tid; c < 512; c += 256) {   // stage K
            const int row = c >> 3, bi = (c & 7) * 16;
            const short8 v = *reinterpret_cast<const short8*>(
                khp + (bhS + k0 + row) * kDH + (c & 7) * 8);
            *reinterpret_cast<short8*>(smem + pKl + row * 128 + (bi ^ ((row & 7) << 4))) = v;
        }
        for (int c = tid; c < 640; c += 256) {   // stage E window (clamped)
            const int row = c >> 3, bi = (c & 7) * 16;
            const int er = min(m_lo + row, kS - 1);
            const short8 v = *reinterpret_cast<const short8*>(
                eb + (size_t)er * kDH + (c & 7) * 8);
            *reinterpret_cast<short8*>(smem + pEl + row * 128 + (bi ^ ((row & 7) << 4))) = v;
        }
        __syncthreads();                         // staged data visible

        f32x4 s4 = {0.f, 0.f, 0.f, 0.f};
        s4 = mfma16(aq0, *reinterpret_cast<const short8*>(smem + pKl + rW * 128 + b0), s4);
        s4 = mfma16(aq1, *reinterpret_cast<const short8*>(smem + pKl + rW * 128 + b1), s4);
        f32x4 qe2[2];
        #pragma unroll
        for (int q2 = 0; q2 < 2; ++q2) {
            const int rE = w * 16 + q2 * 16 + n15;
            f32x4 acc = {0.f, 0.f, 0.f, 0.f};
            acc = mfma16(aq0, *reinterpret_cast<const short8*>(smem + pEl + rE * 128 + b0), acc);
            qe2[q2] = mfma16(aq1, *reinterpret_cast<const short8*>(smem + pEl + rE * 128 + b1), acc);
        }
        ushort* ptile = Pstrip + (size_t)t * 1024;
        #pragma unroll
        for (int j = 0; j < 4; ++j) {
            const float sh0 = __shfl(qe2[0][j], srcl[j]);
            const float sh1 = __shfl(qe2[1][j], srcl[j]);
            const float rel = condj[j] ? sh1 : sh0;
            float v = (s4[j] + rel) * 0.125f;
            v = fminf(v, 60.f);
            const bool keep = (k0 + pcol <= l0 + g * 4 + j);
            const float pe = keep ? __expf(v) : 0.f;
            const short pb = bfbits(pe);
            lsum[j] += bf2f(pb);                 // bf16-consistent normalization
            ptile[(g * 4 + j) * 64 + pcol] = (ushort)pb;
        }
    }
    #pragma unroll
    for (int j = 0; j < 4; ++j) {
        float s = lsum[j];
        #pragma unroll
        for (int off = 1; off < 16; off <<= 1) s += __shfl_xor(s, off);
        if (n15 == 0) lsum_s[w * 16 + g * 4 + j] = s;
    }
    __syncthreads();                             // lsum exchange
    if (tid < 16)
        linv_s[tid] = 1.f / (lsum_s[tid] + lsum_s[16 + tid] +
                             lsum_s[32 + tid] + lsum_s[48 + tid]);
    __syncthreads();                             // linv visible

    // ---------------- pass B: emit + PV (no score recompute) ----------------
    f32x4 o = {0.f, 0.f, 0.f, 0.f};              // wave-private dh-quadrant w
    const int srow = tid >> 4;
    const int scol = (tid & 15) * 4;
    const int sby  = ((tid & 15) * 8) ^ ((srow & 7) << 4);   // swizzled 8B pos

    for (int t = 0; t < 32; ++t) {
        const int k0 = t * 64;
        if (t >= T) {                            // fully masked: zero-fill
            const f32x4 z = {0.f, 0.f, 0.f, 0.f};
            __builtin_nontemporal_store(
                z, reinterpret_cast<f32x4*>(attn + (bhS + l0 + srow) * kS + k0 + scol));
            continue;
        }
        __syncthreads();                         // prior tile's LDS reads done
        for (int c = tid; c < 512; c += 256) {   // stage V^T (over K region)
            const int row = c >> 3, bi = (c & 7) * 16;
            const short8 v = *reinterpret_cast<const short8*>(
                vt + ((size_t)bh * kDH + row) * kS + k0 + (c & 7) * 8);
            *reinterpret_cast<short8*>(smem + pKl + row * 128 + (bi ^ ((row & 7) << 4))) = v;
        }
        {   // load P tile: dense 8B/thread, swizzled LDS dest
            const short4v pv = *reinterpret_cast<const short4v*>(
                Pstrip + (size_t)t * 1024 + tid * 4);
            const int prow = tid >> 4;
            const int pbyte = (tid & 15) * 8;
            *reinterpret_cast<short4v*>(
                smem + pPl + prow * 128 + (pbyte ^ ((prow & 7) << 4))) = pv;
        }
        __syncthreads();                         // staged data visible

        // emit: attn = bf16P * linv, 256B-contiguous row segments
        {
            const short4v pv = *reinterpret_cast<const short4v*>(smem + pPl + srow * 128 + sby);
            const float li = linv_s[srow];
            f32x4 o4;
            #pragma unroll
            for (int i = 0; i < 4; ++i) o4[i] = bf2f(pv[i]) * li;
            __builtin_nontemporal_store(
                o4, reinterpret_cast<f32x4*>(attn + (bhS + l0 + srow) * kS + k0 + scol));
        }
        // PV: A-frags straight from bf16 P LDS; B-frags from V LDS
        const short8 pa0 = *reinterpret_cast<const short8*>(smem + pPl + n15 * 128 + b0);
        const short8 pa1 = *reinterpret_cast<const short8*>(smem + pPl + n15 * 128 + b1);
        o = mfma16(pa0, *reinterpret_cast<const short8*>(smem + pKl + rW * 128 + b0), o);
        o = mfma16(pa1, *reinterpret_cast<const short8*>(smem + pKl + rW * 128 + b1), o);
    }

    // epilogue: scale O by linv, write bf16 (B,S,D)
    const int b = bh >> 3, h = bh & 7;
    #pragma unroll
    for (int j = 0; j < 4; ++j)
        ohb[((size_t)b * kS + l0 + g * 4 + j) * kD + h * kDH + w * 16 + n15] =
            (ushort)bfbits(o[j] * linv_s[g * 4 + j]);
}

// ---------------------------------------------------------------------------
// R15 attention (fallback when ws is too small) — unchanged, proven.
// ---------------------------------------------------------------------------
__global__ __launch_bounds__(256, 4)
void attn_fused_kernel(const ushort* __restrict__ qh, const ushort* __restrict__ khp,
                       const ushort* __restrict__ vt, const ushort* __restrict__ eb,
                       float* __restrict__ attn, ushort* __restrict__ ohb)
{
    __shared__ __align__(16) char smem[31232];
    float* Pf     = (float*)(smem + kPf);
    float* lsum_s = (float*)(smem + kLs);

    const int bh    = blockIdx.x;
    const int strip = 127 - (int)blockIdx.y;
    const int l0    = strip * 16;
    const int tid   = threadIdx.x;
    const int w     = tid >> 6;
    const int lane  = tid & 63;
    const int g     = lane >> 4;
    const int n15   = lane & 15;
    const size_t bhS = (size_t)bh * kS;

    const int T = ((l0 + 15) >> 6) + 1;

    const ushort* qrow = qh + (bhS + l0 + n15) * kDH;
    const short8 aq0 = *reinterpret_cast<const short8*>(qrow + g * 8);
    const short8 aq1 = *reinterpret_cast<const short8*>(qrow + 32 + g * 8);

    int  srcl[4];
    bool condj[4];
    #pragma unroll
    for (int j = 0; j < 4; ++j) {
        const int d = n15 + 15 - (g * 4 + j);
        srcl[j]  = (lane & 48) | (d & 15);
        condj[j] = (d >= 16);
    }

    const int rW = w * 16 + n15;
    const int mS = (n15 & 7) << 4;
    const int b0 = (g * 16) ^ mS;
    const int b1 = (64 + g * 16) ^ mS;

    float lsum[4] = {0.f, 0.f, 0.f, 0.f};
    for (int t = 0; t < T; ++t) {
        const int k0 = t * 64;
        const int m_lo = 2032 + k0 - l0;
        __syncthreads();
        for (int c = tid; c < 512; c += 256) {
            const int row = c >> 3, bi = (c & 7) * 16;
            const short8 v = *reinterpret_cast<const short8*>(
                khp + (bhS + k0 + row) * kDH + (c & 7) * 8);
            *reinterpret_cast<short8*>(smem + kKl + row * 128 + (bi ^ ((row & 7) << 4))) = v;
        }
        for (int c = tid; c < 640; c += 256) {
            const int row = c >> 3, bi = (c & 7) * 16;
            const int er = min(m_lo + row, kS - 1);
            const short8 v = *reinterpret_cast<const short8*>(
                eb + (size_t)er * kDH + (c & 7) * 8);
            *reinterpret_cast<short8*>(smem + kEl + row * 128 + (bi ^ ((row & 7) << 4))) = v;
        }
        __syncthreads();

        f32x4 s4 = {0.f, 0.f, 0.f, 0.f};
        s4 = mfma16(aq0, *reinterpret_cast<const short8*>(smem + kKl + rW * 128 + b0), s4);
        s4 = mfma16(aq1, *reinterpret_cast<const short8*>(smem + kKl + rW * 128 + b1), s4);
        f32x4 qe2[2];
        #pragma unroll
        for (int q2 = 0; q2 < 2; ++q2) {
            const int rE = w * 16 + q2 * 16 + n15;
            f32x4 acc = {0.f, 0.f, 0.f, 0.f};
            acc = mfma16(aq0, *reinterpret_cast<const short8*>(smem + kEl + rE * 128 + b0), acc);
            qe2[q2] = mfma16(aq1, *reinterpret_cast<const short8*>(smem + kEl + rE * 128 + b1), acc);
        }
        #pragma unroll
        for (int j = 0; j < 4; ++j) {
            const float sh0 = __shfl(qe2[0][j], srcl[j]);
            const float sh1 = __shfl(qe2[1][j], srcl[j]);
            const float rel = condj[j] ? sh1 : sh0;
            float v = (s4[j] + rel) * 0.125f;
            v = fminf(v, 60.f);
            const bool keep = (k0 + w * 16 + n15 <= l0 + g * 4 + j);
            lsum[j] += keep ? __expf(v) : 0.f;
        }
    }
    #pragma unroll
    for (int j = 0; j < 4; ++j) {
        float s = lsum[j];
        #pragma unroll
        for (int off = 1; off < 16; off <<= 1) s += __shfl_xor(s, off);
        if (n15 == 0) lsum_s[w * 16 + g * 4 + j] = s;
    }
    __syncthreads();

    float linv[4];
    #pragma unroll
    for (int j = 0; j < 4; ++j) {
        const int r = g * 4 + j;
        linv[j] = 1.f / (lsum_s[r] + lsum_s[16 + r] + lsum_s[32 + r] + lsum_s[48 + r]);
    }

    f32x4 o = {0.f, 0.f, 0.f, 0.f};
    const int srow = tid >> 4;
    const int scol = (tid & 15) * 4;

    for (int t = 0; t < 32; ++t) {
        const int k0 = t * 64;
        if (t >= T) {
            const f32x4 z = {0.f, 0.f, 0.f, 0.f};
            __builtin_nontemporal_store(
                z, reinterpret_cast<f32x4*>(attn + (bhS + l0 + srow) * kS + k0 + scol));
            continue;
        }
        const int m_lo = 2032 + k0 - l0;
        __syncthreads();
        for (int c = tid; c < 512; c += 256) {
            const int row = c >> 3, bi = (c & 7) * 16;
            const short8 v = *reinterpret_cast<const short8*>(
                khp + (bhS + k0 + row) * kDH + (c & 7) * 8);
            *reinterpret_cast<short8*>(smem + kKl + row * 128 + (bi ^ ((row & 7) << 4))) = v;
        }
        for (int c = tid; c < 512; c += 256) {
            const int row = c >> 3, bi = (c & 7) * 16;
            const short8 v = *reinterpret_cast<const short8*>(
                vt + ((size_t)bh * kDH + row) * kS + k0 + (c & 7) * 8);
            *reinterpret_cast<short8*>(smem + kVl + row * 128 + (bi ^ ((row & 7) << 4))) = v;
        }
        for (int c = tid; c < 640; c += 256) {
            const int row = c >> 3, bi = (c & 7) * 16;
            const int er = min(m_lo + row, kS - 1);
            const short8 v = *reinterpret_cast<const short8*>(
                eb + (size_t)er * kDH + (c & 7) * 8);
            *reinterpret_cast<short8*>(smem + kEl + row * 128 + (bi ^ ((row & 7) << 4))) = v;
        }
        __syncthreads();

        f32x4 s4 = {0.f, 0.f, 0.f, 0.f};
        s4 = mfma16(aq0, *reinterpret_cast<const short8*>(smem + kKl + rW * 128 + b0), s4);
        s4 = mfma16(aq1, *reinterpret_cast<const short8*>(smem + kKl + rW * 128 + b1), s4);
        f32x4 qe2[2];
        #pragma unroll
        for (int q2 = 0; q2 < 2; ++q2) {
            const int rE = w * 16 + q2 * 16 + n15;
            f32x4 acc = {0.f, 0.f, 0.f, 0.f};
            acc = mfma16(aq0, *reinterpret_cast<const short8*>(smem + kEl + rE * 128 + b0), acc);
            qe2[q2] = mfma16(aq1, *reinterpret_cast<const short8*>(smem + kEl + rE * 128 + b1), acc);
        }
        #pragma unroll
        for (int j = 0; j < 4; ++j) {
            const float sh0 = __shfl(qe2[0][j], srcl[j]);
            const float sh1 = __shfl(qe2[1][j], srcl[j]);
            const float rel = condj[j] ? sh1 : sh0;
            float v = (s4[j] + rel) * 0.125f;
            v = fminf(v, 60.f);
            const bool keep = (k0 + w * 16 + n15 <= l0 + g * 4 + j);
            const float pe = keep ? __expf(v) * linv[j] : 0.f;
            Pf[(g * 4 + j) * 68 + w * 16 + n15] = pe;
        }
        __syncthreads();

        const f32x4 pv4 = *reinterpret_cast<const f32x4*>(Pf + srow * 68 + scol);
        __builtin_nontemporal_store(
            pv4, reinterpret_cast<f32x4*>(attn + (bhS + l0 + srow) * kS + k0 + scol));

        const f32x4 plo0 = *reinterpret_cast<const f32x4*>(Pf + n15 * 68 + g * 8);
        const f32x4 phi0 = *reinterpret_cast<const f32x4*>(Pf + n15 * 68 + g * 8 + 4);
        const f32x4 plo1 = *reinterpret_cast<const f32x4*>(Pf + n15 * 68 + 32 + g * 8);
        const f32x4 phi1 = *reinterpret_cast<const f32x4*>(Pf + n15 * 68 + 32 + g * 8 + 4);
        short8 pa0, pa1;
        #pragma unroll
        for (int i = 0; i < 4; ++i) {
            pa0[i] = bfbits(plo0[i]); pa0[4 + i] = bfbits(phi0[i]);
            pa1[i] = bfbits(plo1[i]); pa1[4 + i] = bfbits(phi1[i]);
        }
        o = mfma16(pa0, *reinterpret_cast<const short8*>(smem + kVl + rW * 128 + b0), o);
        o = mfma16(pa1, *reinterpret_cast<const short8*>(smem + kVl + rW * 128 + b1), o);
    }

    const int b = bh >> 3, h = bh & 7;
    #pragma unroll
    for (int j = 0; j < 4; ++j)
        ohb[((size_t)b * kS + l0 + g * 4 + j) * kD + h * kDH + w * 16 + n15] =
            (ushort)bfbits(o[j]);
}

// ---------------------------------------------------------------------------
extern "C" void kernel_launch(void* const* d_in, const int* in_sizes, int n_in,
                              void* d_out, int out_size, void* d_ws, size_t ws_size,
                              hipStream_t stream)
{
    const float* q_in = (const float*)d_in[0];
    const float* k_in = (const float*)d_in[1];
    const float* v_in = (const float*)d_in[2];
    const float* Wq = (const float*)d_in[4];
    const float* bq = (const float*)d_in[5];
    const float* Wk = (const float*)d_in[6];
    const float* bk = (const float*)d_in[7];
    const float* Wv = (const float*)d_in[8];
    const float* bv = (const float*)d_in[9];
    const float* Wo = (const float*)d_in[10];
    const float* bo = (const float*)d_in[11];
    const float* E  = (const float*)d_in[12];

    float* out  = (float*)d_out;                          // (B,S,D)
    float* attn = (float*)d_out + (size_t)kB * kS * kD;   // (B,H,S,S)

    // workspace
    ushort* qh  = (ushort*)d_ws;          // (B,H,S,DH)
    ushort* kh  = qh  + 2097152;          // (B,H,S,DH)
    ushort* vt  = kh  + 2097152;          // (B,H,DH,S)
    ushort* ohb = vt  + 2097152;          // (B,S,D)
    ushort* eb  = ohb + 2097152;          // (2048,64)
    ushort* Wqt = eb  + 131072;           // col-major 512x512
    ushort* Wkt = Wqt + 262144;
    ushort* Wvt = Wkt + 262144;
    ushort* Wot = Wvt + 262144;
    ushort* Pws = Wot + 262144;           // packed triangular P (bf16), 69 MB

    const size_t need = (size_t)((char*)(Pws + kPwsElems) - (char*)d_ws);

    convw_kernel<<<dim3(8, 8, 5), 256, 0, stream>>>(Wq, Wk, Wv, Wo, E,
                                                    Wqt, Wkt, Wvt, Wot, eb);
    gemm_qkv_kernel<<<dim3(64, 16, 3), 256, 0, stream>>>(q_in, k_in, v_in,
                                                         Wqt, Wkt, Wvt,
                                                         bq, bk, bv, qh, kh, vt);
    if (ws_size >= need) {
        attn_ps_kernel<<<dim3(16, 128), 256, 0, stream>>>(qh, kh, vt, eb,
                                                          attn, ohb, Pws);
    } else {
        attn_fused_kernel<<<dim3(16, 128), 256, 0, stream>>>(qh, kh, vt, eb,
                                                             attn, ohb);
    }
    gemm_o_kernel<<<dim3(64, 16), 256, 0, stream>>>(ohb, Wot, bo, out);
}